// Round 16
// baseline (633.683 us; speedup 1.0000x reference)
//
#include <hip/hip_runtime.h>
#include <hip/hip_bf16.h>
#include <float.h>

typedef __hip_bfloat16 bf16;
typedef __attribute__((ext_vector_type(8))) __bf16 bfrag;   // MFMA A/B operand (4 VGPRs)
typedef __attribute__((ext_vector_type(4))) float f32x4;    // MFMA C/D operand

#define B_ 32
#define C_ 312
#define N_ 1024
#define H_ 8
#define D_ 128
#define SD_ 78
#define BC_ (B_ * C_)      // 9984
#define BH_ (B_ * H_)      // 256

__device__ __forceinline__ float bf2f(bf16 x) { return __bfloat162float(x); }
__device__ __forceinline__ bf16 f2bf(float x) { return __float2bfloat16(x); }
__device__ __forceinline__ float hswish(float x) {
    return x * fminf(fmaxf(x + 3.0f, 0.0f), 6.0f) * (1.0f / 6.0f);
}

__device__ __forceinline__ void gload_lds16(const void* g, void* l) {
    __builtin_amdgcn_global_load_lds(
        (const __attribute__((address_space(1))) void*)g,
        (__attribute__((address_space(3))) void*)l, 16, 0, 0);
}

// ---------------- LayerNorm (stats only; affine folded into W), float4 ------
__global__ void ln_kernel(const float* __restrict__ x, bf16* __restrict__ xn) {
    int r = blockIdx.x;
    int t = threadIdx.x;
    const float* xr = x + (size_t)r * N_;
    float4 v4 = *reinterpret_cast<const float4*>(xr + t * 4);
    float s = v4.x + v4.y + v4.z + v4.w;
    float sq = v4.x * v4.x + v4.y * v4.y + v4.z * v4.z + v4.w * v4.w;
    __shared__ float rs[256], rq[256];
    rs[t] = s; rq[t] = sq; __syncthreads();
    for (int o = 128; o > 0; o >>= 1) {
        if (t < o) { rs[t] += rs[t + o]; rq[t] += rq[t + o]; }
        __syncthreads();
    }
    float mu = rs[0] * (1.0f / N_);
    float var = rq[0] * (1.0f / N_) - mu * mu;
    float rstd = rsqrtf(var + 1e-5f);
    __bf16 o4[4] = { (__bf16)((v4.x - mu) * rstd), (__bf16)((v4.y - mu) * rstd),
                     (__bf16)((v4.z - mu) * rstd), (__bf16)((v4.w - mu) * rstd) };
    *reinterpret_cast<uint2*>(reinterpret_cast<__bf16*>(xn) + (size_t)r * N_ + t * 4) =
        *reinterpret_cast<const uint2*>(o4);
}

// ---- W preconvert: fold LN gamma into W (bf16), beta into bias row ---------
__global__ void wcvt_kernel(const float* __restrict__ wq, const float* __restrict__ wk,
                            const float* __restrict__ wv, const float* __restrict__ wp,
                            const float* __restrict__ gq, const float* __restrict__ bq,
                            const float* __restrict__ gk, const float* __restrict__ bk,
                            const float* __restrict__ gv, const float* __restrict__ bv_,
                            bf16* __restrict__ wqkv, float* __restrict__ bias3,
                            bf16* __restrict__ wpb) {
    int n = blockIdx.x;          // 0..4095
    int t = threadIdx.x;         // 256
    int k4 = t * 4;
    const float* src; const float* G = nullptr; const float* Bv = nullptr;
    if (n < 1024)      { src = wq + (size_t)n * N_;          G = gq; Bv = bq; }
    else if (n < 2048) { src = wk + (size_t)(n - 1024) * N_; G = gk; Bv = bk; }
    else if (n < 3072) { src = wv + (size_t)(n - 2048) * N_; G = gv; Bv = bv_; }
    else               { src = wp + (size_t)(n - 3072) * N_; }
    float4 w4 = *reinterpret_cast<const float4*>(src + k4);
    if (G) {
        __bf16 o[4] = { (__bf16)(w4.x * G[k4]),     (__bf16)(w4.y * G[k4 + 1]),
                        (__bf16)(w4.z * G[k4 + 2]), (__bf16)(w4.w * G[k4 + 3]) };
        *reinterpret_cast<uint2*>(wqkv + (size_t)n * N_ + k4) = *reinterpret_cast<const uint2*>(o);
        float s = w4.x * Bv[k4] + w4.y * Bv[k4 + 1] + w4.z * Bv[k4 + 2] + w4.w * Bv[k4 + 3];
        __shared__ float rs[256];
        rs[t] = s; __syncthreads();
        for (int o2 = 128; o2 > 0; o2 >>= 1) {
            if (t < o2) rs[t] += rs[t + o2];
            __syncthreads();
        }
        if (t == 0) bias3[n] = rs[0];
    } else {
        __bf16 o[4] = { (__bf16)w4.x, (__bf16)w4.y, (__bf16)w4.z, (__bf16)w4.w };
        *reinterpret_cast<uint2*>(wpb + (size_t)(n - 3072) * N_ + k4) = *reinterpret_cast<const uint2*>(o);
    }
}

// ---------------- MFMA GEMM v3: global_load_lds + XOR-swizzled LDS ----------
template <bool OUTF32>
__global__ __launch_bounds__(256) void mfma_gemm_bw(
        const bf16* __restrict__ A_,
        const bf16* __restrict__ Wb,
        const float* __restrict__ bias, int nTx,
        void* __restrict__ O0, void* __restrict__ O1, void* __restrict__ O2) {
    const int K = 1024, Nout = 1024;
    __shared__ __bf16 sA[128 * 64];
    __shared__ __bf16 sB[128 * 64];
    const __bf16* A = reinterpret_cast<const __bf16*>(A_);
    const __bf16* W = reinterpret_cast<const __bf16*>(Wb);

    int t = threadIdx.x;
    int lane = t & 63, wave = t >> 6;
    int wm = (wave >> 1) * 64, wn = (wave & 1) * 64;
    int quad = lane >> 4, l15 = lane & 15;

    int cpx = gridDim.x >> 3;
    int tile = (blockIdx.x & 7) * cpx + (blockIdx.x >> 3);
    int bx = tile % nTx, by = tile / nTx;
    int m0 = by * 128;
    int w0 = bx * 128;
    int which = bx >> 3;
    int n0 = (bx & 7) * 128;

    int rowLoc = wave * 8 + (lane >> 3);
    int c8s = (lane & 7) ^ (lane >> 3);
    const __bf16* gA = A + (size_t)(m0 + rowLoc) * K + c8s * 8;
    const __bf16* gW = W + (size_t)(w0 + rowLoc) * K + c8s * 8;

    f32x4 acc[4][4];
#pragma unroll
    for (int i = 0; i < 4; i++)
#pragma unroll
        for (int j = 0; j < 4; j++) acc[i][j] = (f32x4)(0.f);

    for (int kt = 0; kt < 16; kt++) {
        int k0 = kt * 64;
#pragma unroll
        for (int cc = 0; cc < 4; cc++) {
            gload_lds16(gA + (size_t)cc * 32 * K + k0, &sA[cc * 2048 + wave * 512]);
            gload_lds16(gW + (size_t)cc * 32 * K + k0, &sB[cc * 2048 + wave * 512]);
        }
        __syncthreads();
#pragma unroll
        for (int kk = 0; kk < 2; kk++) {
            bfrag af[4], bfr[4];
#pragma unroll
            for (int mt = 0; mt < 4; mt++) {
                int row = wm + mt * 16 + l15;
                af[mt] = *reinterpret_cast<const bfrag*>(
                    &sA[(row * 8 + ((kk * 4 + quad) ^ (row & 7))) * 8]);
            }
#pragma unroll
            for (int nt = 0; nt < 4; nt++) {
                int row = wn + nt * 16 + l15;
                bfr[nt] = *reinterpret_cast<const bfrag*>(
                    &sB[(row * 8 + ((kk * 4 + quad) ^ (row & 7))) * 8]);
            }
#pragma unroll
            for (int mt = 0; mt < 4; mt++)
#pragma unroll
                for (int nt = 0; nt < 4; nt++)
                    acc[mt][nt] = __builtin_amdgcn_mfma_f32_16x16x32_bf16(af[mt], bfr[nt], acc[mt][nt], 0, 0, 0);
        }
        __syncthreads();
    }
    void* Cout = which == 0 ? O0 : (which == 1 ? O1 : O2);
#pragma unroll
    for (int mt = 0; mt < 4; mt++) {
#pragma unroll
        for (int nt = 0; nt < 4; nt++) {
            int cloc = wn + nt * 16 + l15;
            float bb = bias ? bias[w0 + cloc] : 0.f;
            int col = n0 + cloc;
#pragma unroll
            for (int r = 0; r < 4; r++) {
                int row = m0 + wm + mt * 16 + quad * 4 + r;
                float v = acc[mt][nt][r] + bb;
                if (OUTF32) ((float*)Cout)[(size_t)row * Nout + col] = v;
                else        ((bf16*)Cout)[(size_t)row * Nout + col] = f2bf(v);
            }
        }
    }
}

// ---------------- aggregator pieces (batched over 3 tensors via blockIdx.y) --
// seg0, vectorized: 4 bf16 per thread; grid (2496, 3)
__global__ void seg0_kernel(const bf16* __restrict__ t0, const bf16* __restrict__ t1,
                            const bf16* __restrict__ t2,
                            bf16* __restrict__ h0, bf16* __restrict__ h1,
                            bf16* __restrict__ h2,
                            const float* __restrict__ g, const float* __restrict__ b,
                            const float* __restrict__ m, const float* __restrict__ v) {
    int ti = blockIdx.y;
    const bf16* tin = ti == 0 ? t0 : (ti == 1 ? t1 : t2);
    bf16* th = ti == 0 ? h0 : (ti == 1 ? h1 : h2);
    int bc = blockIdx.x;
    int bi = bc / SD_, c = bc % SD_;
    float inv = g[c] * rsqrtf(v[c] + 1e-5f);
    float mm = m[c], bb = b[c];
    const __bf16* tp = reinterpret_cast<const __bf16*>(tin) + ((size_t)bi * C_ + c) * N_;
    __bf16* base = reinterpret_cast<__bf16*>(th) + (size_t)bi * H_ * C_ * D_;
    int n = threadIdx.x * 4;
    uint2 in2 = *reinterpret_cast<const uint2*>(tp + n);
    const __bf16* iv = reinterpret_cast<const __bf16*>(&in2);
    __bf16 o4[4];
#pragma unroll
    for (int j = 0; j < 4; j++)
        o4[j] = (__bf16)hswish(((float)iv[j] - mm) * inv + bb);
    *reinterpret_cast<uint2*>(&base[((n >> 7) * C_ + c) * D_ + (n & 127)]) =
        *reinterpret_cast<const uint2*>(o4);
}

// ---- fused depthwise(KS)+pointwise impl, v7: zero-padded rows, no masking --
// sIn rows are [4 pad][32 cols][4 pad] bf16 (40 elems); pads zeroed so the dw
// inner loop is unconditional cvt+fma (v6 spent ~half its VALU on the
// jj-bounds cmp+cndmask per tap). All LDS reads/writes alignment-safe:
// row stride 40 elems (80 B); b128 frag reads at di*40+q8 (+8), 8-elem aligned.
template <int KS, int MODE>
__device__ __forceinline__ void dwpw_impl(
        char* uMem, float* sDwF, float* sWk,
        const bf16* __restrict__ tin, int cOff,
        const float* __restrict__ dw, const float* __restrict__ pw,
        const float* __restrict__ g, const float* __restrict__ b,
        const float* __restrict__ m, const float* __restrict__ v,
        bf16* __restrict__ th, float* __restrict__ rawOut,
        int r0, int bi, int tid) {
    constexpr int WKP = ((KS * KS + 3) / 4) * 4;                // 28 / 12
    __bf16* sIn = reinterpret_cast<__bf16*>(uMem);              // [78][KS][40]
    float (*sWt)[80] = reinterpret_cast<float (*)[80]>(uMem);   // [78][80]
    const int P = KS / 2;

    // phase A-load: zero the 4+4 pad cols of every row (uint2 = 4 bf16)
    for (int u = tid; u < SD_ * KS * 2; u += 512) {
        int rowi = u >> 1, side = u & 1;
        *reinterpret_cast<uint2*>(sIn + rowi * 40 + (side ? 36 : 0)) = make_uint2(0u, 0u);
    }
    // stage KS input rows (zero outside image): uint4 global read -> 2x uint2
    const __bf16* tbase = reinterpret_cast<const __bf16*>(tin) + ((size_t)bi * C_ + cOff) * N_;
    for (int u = tid; u < SD_ * KS * 4; u += 512) {
        int c = u / (KS * 4);
        int rem = u - c * (KS * 4);
        int di = rem >> 2, cb = rem & 3;
        int ii = r0 + di - P;
        uint4 val = make_uint4(0u, 0u, 0u, 0u);
        if (ii >= 0 && ii <= 31)
            val = *reinterpret_cast<const uint4*>(tbase + (size_t)c * N_ + ii * 32 + cb * 8);
        __bf16* dst = sIn + (c * KS + di) * 40 + 4 + cb * 8;
        *reinterpret_cast<uint2*>(dst)     = make_uint2(val.x, val.y);
        *reinterpret_cast<uint2*>(dst + 4) = make_uint2(val.z, val.w);
    }
    // stage dw weights into LDS (padded rows of WKP floats)
    for (int i = tid; i < SD_ * KS * KS; i += 512) {
        int c = i / (KS * KS), q = i - c * (KS * KS);
        sWk[c * WKP + q] = dw[i];
    }
    __syncthreads();

    // phase A-compute: depthwise conv row r0; thread = (c, 8-col group q8).
    // Two b128 windows cover padded cols q8..q8+15; used idx k+dj-P+4 in [4-P, 11+P].
    for (int u = tid; u < SD_ * 4; u += 512) {
        int c = u >> 2, q8 = (u & 3) << 3;
        const __bf16* rbase = sIn + (size_t)(c * KS) * 40;
        __bf16 rowv[KS][16];
#pragma unroll
        for (int di = 0; di < KS; di++) {
            *reinterpret_cast<bfrag*>(&rowv[di][0]) = *reinterpret_cast<const bfrag*>(rbase + di * 40 + q8);
            *reinterpret_cast<bfrag*>(&rowv[di][8]) = *reinterpret_cast<const bfrag*>(rbase + di * 40 + q8 + 8);
        }
        float wreg[WKP];
#pragma unroll
        for (int qq = 0; qq < WKP / 4; qq++)
            *reinterpret_cast<float4*>(&wreg[qq * 4]) =
                *reinterpret_cast<const float4*>(&sWk[c * WKP + qq * 4]);
        float acc8[8];
#pragma unroll
        for (int k = 0; k < 8; k++) acc8[k] = 0.f;
#pragma unroll
        for (int di = 0; di < KS; di++) {
#pragma unroll
            for (int dj = 0; dj < KS; dj++) {
                float w = wreg[di * KS + dj];
#pragma unroll
                for (int k = 0; k < 8; k++)
                    acc8[k] += (float)rowv[di][k + dj - P + 4] * w;
            }
        }
        *reinterpret_cast<float4*>(&sDwF[c * 32 + q8])     = *reinterpret_cast<const float4*>(&acc8[0]);
        *reinterpret_cast<float4*>(&sDwF[c * 32 + q8 + 4]) = *reinterpret_cast<const float4*>(&acc8[4]);
    }
    __syncthreads();

    // phase B-load: pw weights transposed into uMem (cols 78/79 zeroed)
    for (int i = tid; i < SD_ * 80; i += 512) {
        int c = i / 80, o = i - c * 80;
        sWt[c][o] = (o < SD_) ? pw[o * SD_ + c] : 0.f;
    }
    __syncthreads();

    // phase B-compute: pointwise, 5 output channels per thread, 1 position
    int p = tid & 31, og = tid >> 5;   // og 0..15
    int o0 = og * 5;
    int no = (og == 15) ? 3 : 5;       // 75..77
    float acc[5];
#pragma unroll
    for (int i = 0; i < 5; i++) acc[i] = 0.f;
    for (int c = 0; c < SD_; c++) {
        float vv = sDwF[c * 32 + p];
#pragma unroll
        for (int q = 0; q < 5; q++)
            acc[q] += sWt[c][o0 + q] * vv;
    }
    int n = r0 * 32 + p;
    if (MODE == 0) {
        bf16* base = th + (size_t)bi * H_ * C_ * D_;
        for (int j = 0; j < no; j++) {
            int o = o0 + j;
            float inv = g[o] * rsqrtf(v[o] + 1e-5f);
            float y = hswish((acc[j] - m[o]) * inv + b[o]);
            base[((n >> 7) * C_ + cOff + o) * D_ + (n & 127)] = f2bf(y);
        }
    } else {
        float* opr = rawOut + (size_t)bi * SD_ * N_;
        for (int j = 0; j < no; j++)
            opr[(size_t)(o0 + j) * N_ + n] = acc[j];
    }
}

// ---- all three dw+pw branches in ONE launch ---------------------------------
// grid (B*32, 3 tensors, 3 branches), 512 threads. Branches write disjoint
// outputs. LDS: sIn 31200 (union w/ sWt 24960) + sDw 9984 + sWk 8736 = 49.9 KB
// -> 3 blocks/CU, 24 waves/CU.
__global__ __launch_bounds__(512) void dwpw_all_kernel(
        const bf16* __restrict__ t0, const bf16* __restrict__ t1,
        const bf16* __restrict__ t2,
        const float* __restrict__ dw1, const float* __restrict__ pw1,
        const float* __restrict__ g1, const float* __restrict__ b1,
        const float* __restrict__ m1, const float* __restrict__ v1,
        const float* __restrict__ dw2, const float* __restrict__ pw2,
        const float* __restrict__ g2, const float* __restrict__ b2,
        const float* __restrict__ m2, const float* __restrict__ v2,
        const float* __restrict__ dw0, const float* __restrict__ pw0,
        bf16* __restrict__ h0, bf16* __restrict__ h1, bf16* __restrict__ h2,
        float* __restrict__ r0_, float* __restrict__ r1_, float* __restrict__ r2_) {
    __shared__ __align__(16) char uMem[SD_ * 5 * 40 * sizeof(__bf16)];  // 31200 B
    __shared__ __align__(16) float sDwF[SD_ * 32];                      //  9984 B
    __shared__ __align__(16) float sWk[SD_ * 28];                       //  8736 B

    int ti = blockIdx.y;
    const bf16* tin = ti == 0 ? t0 : (ti == 1 ? t1 : t2);
    bf16* th = ti == 0 ? h0 : (ti == 1 ? h1 : h2);
    float* rawOut = ti == 0 ? r0_ : (ti == 1 ? r1_ : r2_);
    int r0 = blockIdx.x & 31;
    int bi = blockIdx.x >> 5;
    int tid = threadIdx.x;
    int branch = blockIdx.z;

    if (branch == 0) {
        dwpw_impl<3, 0>(uMem, sDwF, sWk, tin, SD_, dw1, pw1, g1, b1, m1, v1,
                        th, (float*)nullptr, r0, bi, tid);
    } else if (branch == 1) {
        dwpw_impl<5, 0>(uMem, sDwF, sWk, tin, 2 * SD_, dw2, pw2, g2, b2, m2, v2,
                        th, (float*)nullptr, r0, bi, tid);
    } else {
        dwpw_impl<3, 1>(uMem, sDwF, sWk, tin, 3 * SD_, dw0, pw0,
                        (const float*)nullptr, (const float*)nullptr,
                        (const float*)nullptr, (const float*)nullptr,
                        (bf16*)nullptr, rawOut, r0, bi, tid);
    }
}

// grid (64, 3): stats[ti*128 + bg*2 .. +1]
__global__ void gn_stats_kernel(const float* __restrict__ r0_, const float* __restrict__ r1_,
                                const float* __restrict__ r2_, float* __restrict__ stats) {
    int ti = blockIdx.y;
    const float* tmp2 = ti == 0 ? r0_ : (ti == 1 ? r1_ : r2_);
    int bg = blockIdx.x;
    int bi = bg >> 1, grp = bg & 1;
    const float* p = tmp2 + (size_t)bi * SD_ * N_ + (size_t)grp * 39 * N_;
    float s = 0.f, sq = 0.f;
    const int TOT = 39 * N_;
    for (int i = threadIdx.x * 4; i < TOT; i += 1024) {
        float4 f4 = *reinterpret_cast<const float4*>(p + i);
        s += f4.x + f4.y + f4.z + f4.w;
        sq += f4.x * f4.x + f4.y * f4.y + f4.z * f4.z + f4.w * f4.w;
    }
    __shared__ float rs[256], rq[256];
    rs[threadIdx.x] = s; rq[threadIdx.x] = sq; __syncthreads();
    for (int o = 128; o > 0; o >>= 1) {
        if (threadIdx.x < o) { rs[threadIdx.x] += rs[threadIdx.x + o]; rq[threadIdx.x] += rq[threadIdx.x + o]; }
        __syncthreads();
    }
    if (threadIdx.x == 0) {
        float mu = rs[0] / (float)TOT;
        float var = rq[0] / (float)TOT - mu * mu;
        stats[ti * 128 + bg * 2] = mu;
        stats[ti * 128 + bg * 2 + 1] = rsqrtf(var + 1e-5f);
    }
}

// grid (2496, 3)
__global__ void gn_apply_kernel(const float* __restrict__ r0_, const float* __restrict__ r1_,
                                const float* __restrict__ r2_, const float* __restrict__ stats,
                                const float* __restrict__ gg, const float* __restrict__ gb,
                                bf16* __restrict__ h0, bf16* __restrict__ h1,
                                bf16* __restrict__ h2) {
    int ti = blockIdx.y;
    const float* tmp2 = ti == 0 ? r0_ : (ti == 1 ? r1_ : r2_);
    bf16* th = ti == 0 ? h0 : (ti == 1 ? h1 : h2);
    int bc = blockIdx.x;
    int bi = bc / SD_, c = bc % SD_;
    int grp = c / 39;
    float mu = stats[ti * 128 + (bi * 2 + grp) * 2];
    float rstd = stats[ti * 128 + (bi * 2 + grp) * 2 + 1];
    float sc = gg[c] * rstd;
    float of = gb[c] - mu * sc;
    const float* p = tmp2 + ((size_t)bi * SD_ + c) * N_;
    __bf16* base = reinterpret_cast<__bf16*>(th) + (size_t)bi * H_ * C_ * D_;
    int n = threadIdx.x * 4;
    float4 f4 = *reinterpret_cast<const float4*>(p + n);
    __bf16 o4[4] = { (__bf16)hswish(f4.x * sc + of), (__bf16)hswish(f4.y * sc + of),
                     (__bf16)hswish(f4.z * sc + of), (__bf16)hswish(f4.w * sc + of) };
    *reinterpret_cast<uint2*>(&base[((n >> 7) * C_ + 234 + c) * D_ + (n & 127)]) =
        *reinterpret_cast<const uint2*>(o4);
}

// ---- FUSED attn: scores + GELU + softmax + attn-out + PV -> ctx ------------
#define SLDA 136
#define PLDA 328
__global__ __launch_bounds__(512, 4) void attn_av_kernel(
        const bf16* __restrict__ qh_, const bf16* __restrict__ kh_,
        const bf16* __restrict__ vh_,
        float* __restrict__ attnOut, bf16* __restrict__ ctx) {
    __shared__ __align__(16) char uni[60928];
    __shared__ float smax[64][2];
    __shared__ float ssum[64][2];
    __bf16* sQ = reinterpret_cast<__bf16*>(uni);            // [64][SLDA]
    __bf16* sK = reinterpret_cast<__bf16*>(uni + 17408);    // [160][SLDA]
    __bf16* sP = reinterpret_cast<__bf16*>(uni);            // [64][PLDA]
    __bf16* sV = reinterpret_cast<__bf16*>(uni + 41984);    // [2][8][64][8]
    const __bf16* qh = reinterpret_cast<const __bf16*>(qh_);
    const __bf16* kh = reinterpret_cast<const __bf16*>(kh_);
    const __bf16* vh = reinterpret_cast<const __bf16*>(vh_);

    int strip = blockIdx.x;
    int bh = blockIdx.y;
    int t = threadIdx.x;
    int lane = t & 63, wave = t >> 6;
    int quad = lane >> 4, l15 = lane & 15;
    int wm = wave >> 1;
    int wn = wave & 1;

#pragma unroll
    for (int cc = 0; cc < 2; cc++) {
        int c = t + cc * 512;
        int row = c >> 4, seg = c & 15;
        int src = strip * 64 + row; if (src > 311) src = 311;
        bfrag v = *reinterpret_cast<const bfrag*>(qh + ((size_t)bh * C_ + src) * D_ + seg * 8);
        *reinterpret_cast<bfrag*>(&sQ[row * SLDA + seg * 8]) = v;
    }

    f32x4 acc[10];
#pragma unroll
    for (int i = 0; i < 10; i++) acc[i] = (f32x4)(0.f);

    bfrag af[4];
    bool afLoaded = false;

    for (int half = 0; half < 2; half++) {
        if (half) __syncthreads();
        for (int cc = 0; cc < 5; cc++) {
            int c = t + cc * 512;
            int row = c >> 4, seg = c & 15;
            int src = half * 160 + row;
            bfrag v;
            if (src < C_) {
                v = *reinterpret_cast<const bfrag*>(kh + ((size_t)bh * C_ + src) * D_ + seg * 8);
            } else {
#pragma unroll
                for (int j = 0; j < 8; j++) v[j] = (__bf16)0.f;
            }
            *reinterpret_cast<bfrag*>(&sK[row * SLDA + seg * 8]) = v;
        }
        __syncthreads();
        if (!afLoaded) {
#pragma unroll
            for (int ks = 0; ks < 4; ks++)
                af[ks] = *reinterpret_cast<const bfrag*>(&sQ[(wm * 16 + l15) * SLDA + ks * 32 + quad * 8]);
            afLoaded = true;
        }
#pragma unroll
        for (int ks = 0; ks < 4; ks++) {
#pragma unroll
            for (int jj = 0; jj < 5; jj++) {
                int lr = (wn * 5 + jj) * 16 + l15;
                bfrag bf = *reinterpret_cast<const bfrag*>(&sK[lr * SLDA + ks * 32 + quad * 8]);
                acc[half * 5 + jj] = __builtin_amdgcn_mfma_f32_16x16x32_bf16(af[ks], bf, acc[half * 5 + jj], 0, 0, 0);
            }
        }
    }

    const float scale = 0.08838834764831845f;
    const float inv_sqrt2 = 0.7071067811865475f;
#pragma unroll
    for (int a = 0; a < 10; a++) {
        int gt = (a / 5) * 10 + wn * 5 + (a % 5);
        int col = gt * 16 + l15;
#pragma unroll
        for (int r = 0; r < 4; r++) {
            float v = acc[a][r];
            float ge = 0.5f * v * (1.0f + erff(v * inv_sqrt2));
            float s = ge * scale;
            if (col >= C_) s = -FLT_MAX;
            acc[a][r] = s;
        }
    }
    float mx[4];
#pragma unroll
    for (int r = 0; r < 4; r++) {
        float m = -FLT_MAX;
#pragma unroll
        for (int a = 0; a < 10; a++) m = fmaxf(m, acc[a][r]);
        for (int o = 1; o < 16; o <<= 1) m = fmaxf(m, __shfl_xor(m, o));
        mx[r] = m;
    }
    if (l15 == 0) {
#pragma unroll
        for (int r = 0; r < 4; r++) smax[wm * 16 + quad * 4 + r][wn] = mx[r];
    }
    __syncthreads();
    float sm[4];
#pragma unroll
    for (int r = 0; r < 4; r++) {
        int row = wm * 16 + quad * 4 + r;
        float m = fmaxf(smax[row][0], smax[row][1]);
        float s = 0.f;
#pragma unroll
        for (int a = 0; a < 10; a++) {
            float e = __expf(acc[a][r] - m);
            acc[a][r] = e;
            s += e;
        }
        for (int o = 1; o < 16; o <<= 1) s += __shfl_xor(s, o);
        sm[r] = s;
    }
    if (l15 == 0) {
#pragma unroll
        for (int r = 0; r < 4; r++) ssum[wm * 16 + quad * 4 + r][wn] = sm[r];
    }
    __syncthreads();

#pragma unroll
    for (int r = 0; r < 4; r++) {
        int row = wm * 16 + quad * 4 + r;
        float inv = 1.0f / (ssum[row][0] + ssum[row][1]);
        int grow = strip * 64 + row;
        float* ao = attnOut + ((size_t)bh * C_ + grow) * C_;
#pragma unroll
        for (int a = 0; a < 10; a++) {
            int gt = (a / 5) * 10 + wn * 5 + (a % 5);
            int col = gt * 16 + l15;
            float pv = acc[a][r] * inv;
            if (grow < C_ && col < C_) ao[col] = pv;
            sP[row * PLDA + col] = f2bf(pv);
        }
    }

    // ---- phase 2: PV ----
    f32x4 acc2[4];
#pragma unroll
    for (int i = 0; i < 4; i++) acc2[i] = (f32x4)(0.f);

    auto stageV = [&](int chunk) {
#pragma unroll
        for (int it = 0; it < 2; it++) {
            int g = t + it * 512;
            int d = g & 127;
            int oct = g >> 7;
            int ktl = oct >> 2, quad2 = oct & 3;
            int cb = chunk * 64 + ktl * 32 + quad2 * 8;
            const __bf16* vp = vh + ((size_t)bh * C_ + cb) * D_ + d;
            bfrag v;
            if (cb + 7 < C_) {
#pragma unroll
                for (int j = 0; j < 8; j++) v[j] = vp[(size_t)j * D_];
            } else {
#pragma unroll
                for (int j = 0; j < 8; j++) v[j] = (cb + j < C_) ? vp[(size_t)j * D_] : (__bf16)0.f;
            }
            *reinterpret_cast<bfrag*>(&sV[(((ktl * 8 + (d >> 4)) * 64) + quad2 * 16 + (d & 15)) * 8]) = v;
        }
    };

    stageV(0);
    __syncthreads();

    for (int chunk = 0; chunk < 5; chunk++) {
#pragma unroll
        for (int ktl = 0; ktl < 2; ktl++) {
            bfrag a = *reinterpret_cast<const bfrag*>(
                &sP[(wm * 16 + l15) * PLDA + chunk * 64 + ktl * 32 + quad * 8]);
#pragma unroll
            for (int ntl = 0; ntl < 4; ntl++) {
                int ntg = wn * 4 + ntl;
                bfrag b = *reinterpret_cast<const bfrag*>(&sV[(((ktl * 8 + ntg) * 64) + lane) * 8]);
                acc2[ntl] = __builtin_amdgcn_mfma_f32_16x16x32_bf16(a, b, acc2[ntl], 0, 0, 0);
            }
        }
        if (chunk < 4) {
            __syncthreads();
            stageV(chunk + 1);
            __syncthreads();
        }
    }

    int b = bh >> 3, h = bh & 7;
#pragma unroll
    for (int ntl = 0; ntl < 4; ntl++) {
        int d = wn * 64 + ntl * 16 + l15;
#pragma unroll
        for (int r = 0; r < 4; r++) {
            int c = strip * 64 + wm * 16 + quad * 4 + r;
            if (c < C_) {
                size_t oi = ((size_t)b * C_ + h * 39 + (c >> 3)) * N_ + ((c & 7) << 7) + d;
                ctx[oi] = f2bf(acc2[ntl][r]);
            }
        }
    }
}

// ---------------- L2 row norm (fp32 out), float4 -----------------------------
__global__ void norm_kernel(const float* __restrict__ out3, float* __restrict__ outp) {
    int r = blockIdx.x;
    const float* p = out3 + (size_t)r * N_;
    float4 f4 = *reinterpret_cast<const float4*>(p + threadIdx.x * 4);
    float sq = f4.x * f4.x + f4.y * f4.y + f4.z * f4.z + f4.w * f4.w;
    __shared__ float rq[256];
    rq[threadIdx.x] = sq; __syncthreads();
    for (int o = 128; o > 0; o >>= 1) {
        if (threadIdx.x < o) rq[threadIdx.x] += rq[threadIdx.x + o];
        __syncthreads();
    }
    float inv = 1.0f / fmaxf(sqrtf(rq[0]), 1e-12f);
    float4 o4 = { f4.x * inv, f4.y * inv, f4.z * inv, f4.w * inv };
    *reinterpret_cast<float4*>(outp + (size_t)r * N_ + threadIdx.x * 4) = o4;
}

// ---------------- host orchestration ----------------------------------------
extern "C" void kernel_launch(void* const* d_in, const int* in_sizes, int n_in,
                              void* d_out, int out_size, void* d_ws, size_t ws_size,
                              hipStream_t stream) {
    const float* x      = (const float*)d_in[0];
    const float* ln_q_g = (const float*)d_in[3];
    const float* ln_q_b = (const float*)d_in[4];
    const float* ln_k_g = (const float*)d_in[5];
    const float* ln_k_b = (const float*)d_in[6];
    const float* ln_v_g = (const float*)d_in[7];
    const float* ln_v_b = (const float*)d_in[8];
    const float* w_q    = (const float*)d_in[9];
    const float* w_k    = (const float*)d_in[10];
    const float* w_v    = (const float*)d_in[11];
    const float* w_proj = (const float*)d_in[12];
    const float* b_proj = (const float*)d_in[13];
    const float* dw0    = (const float*)d_in[14];
    const float* pw0    = (const float*)d_in[15];
    const float* gn_g   = (const float*)d_in[16];
    const float* gn_b   = (const float*)d_in[17];
    const float* dw1    = (const float*)d_in[18];
    const float* pw1    = (const float*)d_in[19];
    const float* dw2    = (const float*)d_in[20];
    const float* pw2    = (const float*)d_in[21];
    const float* bn0_g  = (const float*)d_in[22];
    const float* bn0_b  = (const float*)d_in[23];
    const float* bn0_m  = (const float*)d_in[24];
    const float* bn0_v  = (const float*)d_in[25];
    const float* bn1_g  = (const float*)d_in[26];
    const float* bn1_b  = (const float*)d_in[27];
    const float* bn1_m  = (const float*)d_in[28];
    const float* bn1_v  = (const float*)d_in[29];
    const float* bn2_g  = (const float*)d_in[30];
    const float* bn2_b  = (const float*)d_in[31];
    const float* bn2_m  = (const float*)d_in[32];
    const float* bn2_v  = (const float*)d_in[33];

    char* ws = (char*)d_ws;
    size_t off = 0;
    auto alloc = [&](size_t bytes) {
        void* p = ws + off;
        off = (off + bytes + 255) & ~(size_t)255;
        return p;
    };
    const size_t BF_BYTES = (size_t)BC_ * N_ * sizeof(bf16);
    const size_t T2_FLOATS = (size_t)B_ * SD_ * N_;
    bf16*  xn   = (bf16*)alloc(BF_BYTES);
    bf16*  qb   = (bf16*)alloc(BF_BYTES);
    bf16*  kb   = (bf16*)alloc(BF_BYTES);
    bf16*  vb   = (bf16*)alloc(BF_BYTES);
    float* tmp2 = (float*)alloc(3 * T2_FLOATS * sizeof(float));       // 38.3 MB
    float* gnst = (float*)alloc(2048);
    bf16*  wqkv = (bf16*)alloc((size_t)3 * N_ * N_ * sizeof(bf16));   // 6 MB
    float* bias3 = (float*)alloc((size_t)3 * N_ * sizeof(float));
    bf16*  wpb  = (bf16*)alloc((size_t)N_ * N_ * sizeof(bf16));       // 2 MB

    float* out_main = (float*)d_out;
    float* attn_out = out_main + (size_t)BC_ * N_;

    bf16* qh  = xn;
    bf16* kh  = (bf16*)out_main;
    bf16* vh  = kh + (size_t)BC_ * N_;
    bf16* ctx = vb;
    float* out3 = (float*)qb;
    float* r0 = tmp2, *r1 = tmp2 + T2_FLOATS, *r2 = tmp2 + 2 * T2_FLOATS;

    hipLaunchKernelGGL(wcvt_kernel, dim3(4096), dim3(256), 0, stream,
                       w_q, w_k, w_v, w_proj,
                       ln_q_g, ln_q_b, ln_k_g, ln_k_b, ln_v_g, ln_v_b,
                       wqkv, bias3, wpb);
    hipLaunchKernelGGL(ln_kernel, dim3(BC_), dim3(256), 0, stream, x, xn);
    hipLaunchKernelGGL((mfma_gemm_bw<false>), dim3(24 * 78), dim3(256), 0, stream,
                       xn, wqkv, bias3, 24, (void*)qb, (void*)kb, (void*)vb);

    hipLaunchKernelGGL(seg0_kernel, dim3(B_ * SD_, 3), dim3(256), 0, stream,
                       qb, kb, vb, qh, kh, vh, bn0_g, bn0_b, bn0_m, bn0_v);
    hipLaunchKernelGGL(dwpw_all_kernel, dim3(B_ * 32, 3, 3), dim3(512), 0, stream,
                       qb, kb, vb,
                       dw1, pw1, bn1_g, bn1_b, bn1_m, bn1_v,
                       dw2, pw2, bn2_g, bn2_b, bn2_m, bn2_v,
                       dw0, pw0,
                       qh, kh, vh, r0, r1, r2);
    hipLaunchKernelGGL(gn_stats_kernel, dim3(B_ * 2, 3), dim3(256), 0, stream,
                       r0, r1, r2, gnst);
    hipLaunchKernelGGL(gn_apply_kernel, dim3(B_ * SD_, 3), dim3(256), 0, stream,
                       r0, r1, r2, gnst, gn_g, gn_b, qh, kh, vh);

    hipLaunchKernelGGL(attn_av_kernel, dim3(5, BH_), dim3(512), 0, stream,
                       qh, kh, vh, attn_out, ctx);
    hipLaunchKernelGGL((mfma_gemm_bw<true>), dim3(8 * 78), dim3(256), 0, stream,
                       ctx, wpb, b_proj, 8, (void*)out3, (void*)out3, (void*)out3);
    hipLaunchKernelGGL(norm_kernel, dim3(BC_), dim3(256), 0, stream, out3, out_main);
}

// Round 17
// 560.643 us; speedup vs baseline: 1.1303x; 1.1303x over previous
//
#include <hip/hip_runtime.h>
#include <hip/hip_bf16.h>
#include <float.h>

typedef __hip_bfloat16 bf16;
typedef __attribute__((ext_vector_type(8))) __bf16 bfrag;   // MFMA A/B operand (4 VGPRs)
typedef __attribute__((ext_vector_type(4))) float f32x4;    // MFMA C/D operand

#define B_ 32
#define C_ 312
#define N_ 1024
#define H_ 8
#define D_ 128
#define SD_ 78
#define BC_ (B_ * C_)      // 9984
#define BH_ (B_ * H_)      // 256

__device__ __forceinline__ float bf2f(bf16 x) { return __bfloat162float(x); }
__device__ __forceinline__ bf16 f2bf(float x) { return __float2bfloat16(x); }
__device__ __forceinline__ float hswish(float x) {
    return x * fminf(fmaxf(x + 3.0f, 0.0f), 6.0f) * (1.0f / 6.0f);
}

__device__ __forceinline__ void gload_lds16(const void* g, void* l) {
    __builtin_amdgcn_global_load_lds(
        (const __attribute__((address_space(1))) void*)g,
        (__attribute__((address_space(3))) void*)l, 16, 0, 0);
}

// ---------------- LayerNorm (stats only; affine folded into W), float4 ------
__global__ void ln_kernel(const float* __restrict__ x, bf16* __restrict__ xn) {
    int r = blockIdx.x;
    int t = threadIdx.x;
    const float* xr = x + (size_t)r * N_;
    float4 v4 = *reinterpret_cast<const float4*>(xr + t * 4);
    float s = v4.x + v4.y + v4.z + v4.w;
    float sq = v4.x * v4.x + v4.y * v4.y + v4.z * v4.z + v4.w * v4.w;
    __shared__ float rs[256], rq[256];
    rs[t] = s; rq[t] = sq; __syncthreads();
    for (int o = 128; o > 0; o >>= 1) {
        if (t < o) { rs[t] += rs[t + o]; rq[t] += rq[t + o]; }
        __syncthreads();
    }
    float mu = rs[0] * (1.0f / N_);
    float var = rq[0] * (1.0f / N_) - mu * mu;
    float rstd = rsqrtf(var + 1e-5f);
    __bf16 o4[4] = { (__bf16)((v4.x - mu) * rstd), (__bf16)((v4.y - mu) * rstd),
                     (__bf16)((v4.z - mu) * rstd), (__bf16)((v4.w - mu) * rstd) };
    *reinterpret_cast<uint2*>(reinterpret_cast<__bf16*>(xn) + (size_t)r * N_ + t * 4) =
        *reinterpret_cast<const uint2*>(o4);
}

// ---- W preconvert: fold LN gamma into W (bf16), beta into bias row ---------
__global__ void wcvt_kernel(const float* __restrict__ wq, const float* __restrict__ wk,
                            const float* __restrict__ wv, const float* __restrict__ wp,
                            const float* __restrict__ gq, const float* __restrict__ bq,
                            const float* __restrict__ gk, const float* __restrict__ bk,
                            const float* __restrict__ gv, const float* __restrict__ bv_,
                            bf16* __restrict__ wqkv, float* __restrict__ bias3,
                            bf16* __restrict__ wpb) {
    int n = blockIdx.x;          // 0..4095
    int t = threadIdx.x;         // 256
    int k4 = t * 4;
    const float* src; const float* G = nullptr; const float* Bv = nullptr;
    if (n < 1024)      { src = wq + (size_t)n * N_;          G = gq; Bv = bq; }
    else if (n < 2048) { src = wk + (size_t)(n - 1024) * N_; G = gk; Bv = bk; }
    else if (n < 3072) { src = wv + (size_t)(n - 2048) * N_; G = gv; Bv = bv_; }
    else               { src = wp + (size_t)(n - 3072) * N_; }
    float4 w4 = *reinterpret_cast<const float4*>(src + k4);
    if (G) {
        __bf16 o[4] = { (__bf16)(w4.x * G[k4]),     (__bf16)(w4.y * G[k4 + 1]),
                        (__bf16)(w4.z * G[k4 + 2]), (__bf16)(w4.w * G[k4 + 3]) };
        *reinterpret_cast<uint2*>(wqkv + (size_t)n * N_ + k4) = *reinterpret_cast<const uint2*>(o);
        float s = w4.x * Bv[k4] + w4.y * Bv[k4 + 1] + w4.z * Bv[k4 + 2] + w4.w * Bv[k4 + 3];
        __shared__ float rs[256];
        rs[t] = s; __syncthreads();
        for (int o2 = 128; o2 > 0; o2 >>= 1) {
            if (t < o2) rs[t] += rs[t + o2];
            __syncthreads();
        }
        if (t == 0) bias3[n] = rs[0];
    } else {
        __bf16 o[4] = { (__bf16)w4.x, (__bf16)w4.y, (__bf16)w4.z, (__bf16)w4.w };
        *reinterpret_cast<uint2*>(wpb + (size_t)(n - 3072) * N_ + k4) = *reinterpret_cast<const uint2*>(o);
    }
}

// ---------------- MFMA GEMM v3: global_load_lds + XOR-swizzled LDS ----------
template <bool OUTF32>
__global__ __launch_bounds__(256) void mfma_gemm_bw(
        const bf16* __restrict__ A_,
        const bf16* __restrict__ Wb,
        const float* __restrict__ bias, int nTx,
        void* __restrict__ O0, void* __restrict__ O1, void* __restrict__ O2) {
    const int K = 1024, Nout = 1024;
    __shared__ __bf16 sA[128 * 64];
    __shared__ __bf16 sB[128 * 64];
    const __bf16* A = reinterpret_cast<const __bf16*>(A_);
    const __bf16* W = reinterpret_cast<const __bf16*>(Wb);

    int t = threadIdx.x;
    int lane = t & 63, wave = t >> 6;
    int wm = (wave >> 1) * 64, wn = (wave & 1) * 64;
    int quad = lane >> 4, l15 = lane & 15;

    int cpx = gridDim.x >> 3;
    int tile = (blockIdx.x & 7) * cpx + (blockIdx.x >> 3);
    int bx = tile % nTx, by = tile / nTx;
    int m0 = by * 128;
    int w0 = bx * 128;
    int which = bx >> 3;
    int n0 = (bx & 7) * 128;

    int rowLoc = wave * 8 + (lane >> 3);
    int c8s = (lane & 7) ^ (lane >> 3);
    const __bf16* gA = A + (size_t)(m0 + rowLoc) * K + c8s * 8;
    const __bf16* gW = W + (size_t)(w0 + rowLoc) * K + c8s * 8;

    f32x4 acc[4][4];
#pragma unroll
    for (int i = 0; i < 4; i++)
#pragma unroll
        for (int j = 0; j < 4; j++) acc[i][j] = (f32x4)(0.f);

    for (int kt = 0; kt < 16; kt++) {
        int k0 = kt * 64;
#pragma unroll
        for (int cc = 0; cc < 4; cc++) {
            gload_lds16(gA + (size_t)cc * 32 * K + k0, &sA[cc * 2048 + wave * 512]);
            gload_lds16(gW + (size_t)cc * 32 * K + k0, &sB[cc * 2048 + wave * 512]);
        }
        __syncthreads();
#pragma unroll
        for (int kk = 0; kk < 2; kk++) {
            bfrag af[4], bfr[4];
#pragma unroll
            for (int mt = 0; mt < 4; mt++) {
                int row = wm + mt * 16 + l15;
                af[mt] = *reinterpret_cast<const bfrag*>(
                    &sA[(row * 8 + ((kk * 4 + quad) ^ (row & 7))) * 8]);
            }
#pragma unroll
            for (int nt = 0; nt < 4; nt++) {
                int row = wn + nt * 16 + l15;
                bfr[nt] = *reinterpret_cast<const bfrag*>(
                    &sB[(row * 8 + ((kk * 4 + quad) ^ (row & 7))) * 8]);
            }
#pragma unroll
            for (int mt = 0; mt < 4; mt++)
#pragma unroll
                for (int nt = 0; nt < 4; nt++)
                    acc[mt][nt] = __builtin_amdgcn_mfma_f32_16x16x32_bf16(af[mt], bfr[nt], acc[mt][nt], 0, 0, 0);
        }
        __syncthreads();
    }
    void* Cout = which == 0 ? O0 : (which == 1 ? O1 : O2);
#pragma unroll
    for (int mt = 0; mt < 4; mt++) {
#pragma unroll
        for (int nt = 0; nt < 4; nt++) {
            int cloc = wn + nt * 16 + l15;
            float bb = bias ? bias[w0 + cloc] : 0.f;
            int col = n0 + cloc;
#pragma unroll
            for (int r = 0; r < 4; r++) {
                int row = m0 + wm + mt * 16 + quad * 4 + r;
                float v = acc[mt][nt][r] + bb;
                if (OUTF32) ((float*)Cout)[(size_t)row * Nout + col] = v;
                else        ((bf16*)Cout)[(size_t)row * Nout + col] = f2bf(v);
            }
        }
    }
}

// ---------------- aggregator pieces (batched over 3 tensors via blockIdx.y) --
// seg0, vectorized: 4 bf16 per thread; grid (2496, 3)
__global__ void seg0_kernel(const bf16* __restrict__ t0, const bf16* __restrict__ t1,
                            const bf16* __restrict__ t2,
                            bf16* __restrict__ h0, bf16* __restrict__ h1,
                            bf16* __restrict__ h2,
                            const float* __restrict__ g, const float* __restrict__ b,
                            const float* __restrict__ m, const float* __restrict__ v) {
    int ti = blockIdx.y;
    const bf16* tin = ti == 0 ? t0 : (ti == 1 ? t1 : t2);
    bf16* th = ti == 0 ? h0 : (ti == 1 ? h1 : h2);
    int bc = blockIdx.x;
    int bi = bc / SD_, c = bc % SD_;
    float inv = g[c] * rsqrtf(v[c] + 1e-5f);
    float mm = m[c], bb = b[c];
    const __bf16* tp = reinterpret_cast<const __bf16*>(tin) + ((size_t)bi * C_ + c) * N_;
    __bf16* base = reinterpret_cast<__bf16*>(th) + (size_t)bi * H_ * C_ * D_;
    int n = threadIdx.x * 4;
    uint2 in2 = *reinterpret_cast<const uint2*>(tp + n);
    const __bf16* iv = reinterpret_cast<const __bf16*>(&in2);
    __bf16 o4[4];
#pragma unroll
    for (int j = 0; j < 4; j++)
        o4[j] = (__bf16)hswish(((float)iv[j] - mm) * inv + bb);
    *reinterpret_cast<uint2*>(&base[((n >> 7) * C_ + c) * D_ + (n & 127)]) =
        *reinterpret_cast<const uint2*>(o4);
}

// ---- fused depthwise(KS) + MFMA pointwise, v8 ------------------------------
// Block = (tensor, batch, 2-row strip = 64 positions), 512 threads / 8 waves.
// dw: v7's proven padded/unconditional taps, output -> dwT bf16 [64 pos][96 c]
// (cols 78..95 zeroed = K padding). pw: MFMA GEMM out[o,pos] = W[o,c]*dw[c,pos]
// using the proven GEMM fragment pattern (A=sWm[m=l15][k], B=dwT[n=l15][k]).
// Replaces pw's 390 fma + 468 ds_read per thread with 30 MFMA per block.
template <int KS, int MODE>
__device__ __forceinline__ void dwpw_impl(
        char* uMem, float* sWk, __bf16* dwT,
        const bf16* __restrict__ tin, int cOff,
        const float* __restrict__ dw, const float* __restrict__ pw,
        const float* __restrict__ g, const float* __restrict__ b,
        const float* __restrict__ m, const float* __restrict__ v,
        bf16* __restrict__ th, float* __restrict__ rawOut,
        int strip, int bi, int tid) {
    constexpr int WKP = ((KS * KS + 3) / 4) * 4;     // 28 / 12
    constexpr int NR  = KS + 1;                      // staged input rows
    __bf16* sIn = reinterpret_cast<__bf16*>(uMem);   // [78][NR][40]
    __bf16* sWm = reinterpret_cast<__bf16*>(uMem);   // [80][96] (after dw)
    const int P = KS / 2;

    // zero pads of sIn rows (uint2 = 4 bf16)
    for (int u = tid; u < SD_ * NR * 2; u += 512) {
        int rowi = u >> 1, side = u & 1;
        *reinterpret_cast<uint2*>(sIn + rowi * 40 + (side ? 36 : 0)) = make_uint2(0u, 0u);
    }
    // zero dwT K-pad cols 78..95 (9 x b32 per pos)
    for (int u = tid; u < 64 * 9; u += 512) {
        int pos = u / 9, cc = 78 + (u % 9) * 2;
        *reinterpret_cast<unsigned int*>(dwT + pos * 96 + cc) = 0u;
    }
    // stage NR input rows (zero outside image): uint4 read -> 2x uint2 LDS
    const __bf16* tbase = reinterpret_cast<const __bf16*>(tin) + ((size_t)bi * C_ + cOff) * N_;
    for (int u = tid; u < SD_ * NR * 4; u += 512) {
        int c = u / (NR * 4);
        int rem = u - c * (NR * 4);
        int di = rem >> 2, cb = rem & 3;
        int ii = 2 * strip + di - P;
        uint4 val = make_uint4(0u, 0u, 0u, 0u);
        if (ii >= 0 && ii <= 31)
            val = *reinterpret_cast<const uint4*>(tbase + (size_t)c * N_ + ii * 32 + cb * 8);
        __bf16* dst = sIn + (c * NR + di) * 40 + 4 + cb * 8;
        *reinterpret_cast<uint2*>(dst)     = make_uint2(val.x, val.y);
        *reinterpret_cast<uint2*>(dst + 4) = make_uint2(val.z, val.w);
    }
    // stage dw weights
    for (int i = tid; i < SD_ * KS * KS; i += 512) {
        int c = i / (KS * KS), q = i - c * (KS * KS);
        sWk[c * WKP + q] = dw[i];
    }
    __syncthreads();

    // dw compute: unit = (c, row 0/1, 8-col group q8) -> dwT[pos][c] bf16
    for (int u = tid; u < SD_ * 8; u += 512) {
        int c = u >> 3, grp = u & 7;
        int row = grp >> 2, q8 = (grp & 3) << 3;
        const __bf16* rbase = sIn + (size_t)(c * NR + row) * 40;
        __bf16 rowv[KS][16];
#pragma unroll
        for (int di = 0; di < KS; di++) {
            *reinterpret_cast<bfrag*>(&rowv[di][0]) = *reinterpret_cast<const bfrag*>(rbase + di * 40 + q8);
            *reinterpret_cast<bfrag*>(&rowv[di][8]) = *reinterpret_cast<const bfrag*>(rbase + di * 40 + q8 + 8);
        }
        float wreg[WKP];
#pragma unroll
        for (int qq = 0; qq < WKP / 4; qq++)
            *reinterpret_cast<float4*>(&wreg[qq * 4]) =
                *reinterpret_cast<const float4*>(&sWk[c * WKP + qq * 4]);
        float acc8[8];
#pragma unroll
        for (int k = 0; k < 8; k++) acc8[k] = 0.f;
#pragma unroll
        for (int di = 0; di < KS; di++) {
#pragma unroll
            for (int dj = 0; dj < KS; dj++) {
                float w = wreg[di * KS + dj];
#pragma unroll
                for (int k = 0; k < 8; k++)
                    acc8[k] += (float)rowv[di][k + dj - P + 4] * w;
            }
        }
#pragma unroll
        for (int k = 0; k < 8; k++)
            dwT[(row * 32 + q8 + k) * 96 + c] = (__bf16)acc8[k];
    }
    __syncthreads();

    // stage pw weights bf16 into sWm [80][96] (o>=78 or c>=78 zero)
    for (int u = tid; u < 80 * 96; u += 512) {
        int o = u / 96, c = u - o * 96;
        float val = (o < SD_ && c < SD_) ? pw[o * SD_ + c] : 0.f;
        sWm[u] = (__bf16)val;
    }
    __syncthreads();

    // MFMA pw: wave w: n-tile = w&3 (16 pos), m-set = (w>>2)? {3,4} : {0,1,2}
    int lane = tid & 63, wave = tid >> 6;
    int quad = lane >> 4, l15 = lane & 15;
    int wn = wave & 3, mh = wave >> 2;
    int mt0 = mh ? 3 : 0;
    int mcnt = mh ? 2 : 3;
    f32x4 acc[3];
#pragma unroll
    for (int i = 0; i < 3; i++) acc[i] = (f32x4)(0.f);
#pragma unroll
    for (int kk = 0; kk < 3; kk++) {
        bfrag bv = *reinterpret_cast<const bfrag*>(dwT + (wn * 16 + l15) * 96 + kk * 32 + quad * 8);
#pragma unroll
        for (int mi = 0; mi < 3; mi++) {
            if (mi < mcnt) {
                bfrag av = *reinterpret_cast<const bfrag*>(sWm + ((mt0 + mi) * 16 + l15) * 96 + kk * 32 + quad * 8);
                acc[mi] = __builtin_amdgcn_mfma_f32_16x16x32_bf16(av, bv, acc[mi], 0, 0, 0);
            }
        }
    }
    // epilogue: o = (mt0+mi)*16 + quad*4 + r, pos = wn*16 + l15
    int n = strip * 64 + wn * 16 + l15;
    if (MODE == 0) {
        bf16* base = th + (size_t)bi * H_ * C_ * D_;
#pragma unroll
        for (int mi = 0; mi < 3; mi++) {
            if (mi < mcnt) {
#pragma unroll
                for (int r = 0; r < 4; r++) {
                    int o = (mt0 + mi) * 16 + quad * 4 + r;
                    if (o < SD_) {
                        float inv = g[o] * rsqrtf(v[o] + 1e-5f);
                        float y = hswish((acc[mi][r] - m[o]) * inv + b[o]);
                        base[((n >> 7) * C_ + cOff + o) * D_ + (n & 127)] = f2bf(y);
                    }
                }
            }
        }
    } else {
        float* opr = rawOut + (size_t)bi * SD_ * N_;
#pragma unroll
        for (int mi = 0; mi < 3; mi++) {
            if (mi < mcnt) {
#pragma unroll
                for (int r = 0; r < 4; r++) {
                    int o = (mt0 + mi) * 16 + quad * 4 + r;
                    if (o < SD_) opr[(size_t)o * N_ + n] = acc[mi][r];
                }
            }
        }
    }
}

// ---- all three dw+pw branches in ONE launch ---------------------------------
// grid (B*16, 3 tensors, 3 branches), 512 threads. LDS: sIn 37440 (union sWm
// 15360) + sWk 8736 + dwT 12288 = 58464 B -> 2 blocks/CU (16 waves).
__global__ __launch_bounds__(512) void dwpw_all_kernel(
        const bf16* __restrict__ t0, const bf16* __restrict__ t1,
        const bf16* __restrict__ t2,
        const float* __restrict__ dw1, const float* __restrict__ pw1,
        const float* __restrict__ g1, const float* __restrict__ b1,
        const float* __restrict__ m1, const float* __restrict__ v1,
        const float* __restrict__ dw2, const float* __restrict__ pw2,
        const float* __restrict__ g2, const float* __restrict__ b2,
        const float* __restrict__ m2, const float* __restrict__ v2,
        const float* __restrict__ dw0, const float* __restrict__ pw0,
        bf16* __restrict__ h0, bf16* __restrict__ h1, bf16* __restrict__ h2,
        float* __restrict__ r0_, float* __restrict__ r1_, float* __restrict__ r2_) {
    __shared__ __align__(16) char uMem[SD_ * 6 * 40 * sizeof(__bf16)];  // 37440 B
    __shared__ __align__(16) float sWk[SD_ * 28];                       //  8736 B
    __shared__ __align__(16) __bf16 dwT[64 * 96];                       // 12288 B

    int ti = blockIdx.y;
    const bf16* tin = ti == 0 ? t0 : (ti == 1 ? t1 : t2);
    bf16* th = ti == 0 ? h0 : (ti == 1 ? h1 : h2);
    float* rawOut = ti == 0 ? r0_ : (ti == 1 ? r1_ : r2_);
    int strip = blockIdx.x & 15;      // 16 strips of 2 rows
    int bi = blockIdx.x >> 4;         // batch
    int tid = threadIdx.x;
    int branch = blockIdx.z;

    if (branch == 0) {
        dwpw_impl<3, 0>(uMem, sWk, dwT, tin, SD_, dw1, pw1, g1, b1, m1, v1,
                        th, (float*)nullptr, strip, bi, tid);
    } else if (branch == 1) {
        dwpw_impl<5, 0>(uMem, sWk, dwT, tin, 2 * SD_, dw2, pw2, g2, b2, m2, v2,
                        th, (float*)nullptr, strip, bi, tid);
    } else {
        dwpw_impl<3, 1>(uMem, sWk, dwT, tin, 3 * SD_, dw0, pw0,
                        (const float*)nullptr, (const float*)nullptr,
                        (const float*)nullptr, (const float*)nullptr,
                        (bf16*)nullptr, rawOut, strip, bi, tid);
    }
}

// grid (64, 3): stats[ti*128 + bg*2 .. +1]
__global__ void gn_stats_kernel(const float* __restrict__ r0_, const float* __restrict__ r1_,
                                const float* __restrict__ r2_, float* __restrict__ stats) {
    int ti = blockIdx.y;
    const float* tmp2 = ti == 0 ? r0_ : (ti == 1 ? r1_ : r2_);
    int bg = blockIdx.x;
    int bi = bg >> 1, grp = bg & 1;
    const float* p = tmp2 + (size_t)bi * SD_ * N_ + (size_t)grp * 39 * N_;
    float s = 0.f, sq = 0.f;
    const int TOT = 39 * N_;
    for (int i = threadIdx.x * 4; i < TOT; i += 1024) {
        float4 f4 = *reinterpret_cast<const float4*>(p + i);
        s += f4.x + f4.y + f4.z + f4.w;
        sq += f4.x * f4.x + f4.y * f4.y + f4.z * f4.z + f4.w * f4.w;
    }
    __shared__ float rs[256], rq[256];
    rs[threadIdx.x] = s; rq[threadIdx.x] = sq; __syncthreads();
    for (int o = 128; o > 0; o >>= 1) {
        if (threadIdx.x < o) { rs[threadIdx.x] += rs[threadIdx.x + o]; rq[threadIdx.x] += rq[threadIdx.x + o]; }
        __syncthreads();
    }
    if (threadIdx.x == 0) {
        float mu = rs[0] / (float)TOT;
        float var = rq[0] / (float)TOT - mu * mu;
        stats[ti * 128 + bg * 2] = mu;
        stats[ti * 128 + bg * 2 + 1] = rsqrtf(var + 1e-5f);
    }
}

// grid (2496, 3)
__global__ void gn_apply_kernel(const float* __restrict__ r0_, const float* __restrict__ r1_,
                                const float* __restrict__ r2_, const float* __restrict__ stats,
                                const float* __restrict__ gg, const float* __restrict__ gb,
                                bf16* __restrict__ h0, bf16* __restrict__ h1,
                                bf16* __restrict__ h2) {
    int ti = blockIdx.y;
    const float* tmp2 = ti == 0 ? r0_ : (ti == 1 ? r1_ : r2_);
    bf16* th = ti == 0 ? h0 : (ti == 1 ? h1 : h2);
    int bc = blockIdx.x;
    int bi = bc / SD_, c = bc % SD_;
    int grp = c / 39;
    float mu = stats[ti * 128 + (bi * 2 + grp) * 2];
    float rstd = stats[ti * 128 + (bi * 2 + grp) * 2 + 1];
    float sc = gg[c] * rstd;
    float of = gb[c] - mu * sc;
    const float* p = tmp2 + ((size_t)bi * SD_ + c) * N_;
    __bf16* base = reinterpret_cast<__bf16*>(th) + (size_t)bi * H_ * C_ * D_;
    int n = threadIdx.x * 4;
    float4 f4 = *reinterpret_cast<const float4*>(p + n);
    __bf16 o4[4] = { (__bf16)hswish(f4.x * sc + of), (__bf16)hswish(f4.y * sc + of),
                     (__bf16)hswish(f4.z * sc + of), (__bf16)hswish(f4.w * sc + of) };
    *reinterpret_cast<uint2*>(&base[((n >> 7) * C_ + 234 + c) * D_ + (n & 127)]) =
        *reinterpret_cast<const uint2*>(o4);
}

// ---- FUSED attn: scores + GELU + softmax + attn-out + PV -> ctx ------------
#define SLDA 136
#define PLDA 328
__global__ __launch_bounds__(512, 4) void attn_av_kernel(
        const bf16* __restrict__ qh_, const bf16* __restrict__ kh_,
        const bf16* __restrict__ vh_,
        float* __restrict__ attnOut, bf16* __restrict__ ctx) {
    __shared__ __align__(16) char uni[60928];
    __shared__ float smax[64][2];
    __shared__ float ssum[64][2];
    __bf16* sQ = reinterpret_cast<__bf16*>(uni);            // [64][SLDA]
    __bf16* sK = reinterpret_cast<__bf16*>(uni + 17408);    // [160][SLDA]
    __bf16* sP = reinterpret_cast<__bf16*>(uni);            // [64][PLDA]
    __bf16* sV = reinterpret_cast<__bf16*>(uni + 41984);    // [2][8][64][8]
    const __bf16* qh = reinterpret_cast<const __bf16*>(qh_);
    const __bf16* kh = reinterpret_cast<const __bf16*>(kh_);
    const __bf16* vh = reinterpret_cast<const __bf16*>(vh_);

    int strip = blockIdx.x;
    int bh = blockIdx.y;
    int t = threadIdx.x;
    int lane = t & 63, wave = t >> 6;
    int quad = lane >> 4, l15 = lane & 15;
    int wm = wave >> 1;
    int wn = wave & 1;

#pragma unroll
    for (int cc = 0; cc < 2; cc++) {
        int c = t + cc * 512;
        int row = c >> 4, seg = c & 15;
        int src = strip * 64 + row; if (src > 311) src = 311;
        bfrag v = *reinterpret_cast<const bfrag*>(qh + ((size_t)bh * C_ + src) * D_ + seg * 8);
        *reinterpret_cast<bfrag*>(&sQ[row * SLDA + seg * 8]) = v;
    }

    f32x4 acc[10];
#pragma unroll
    for (int i = 0; i < 10; i++) acc[i] = (f32x4)(0.f);

    bfrag af[4];
    bool afLoaded = false;

    for (int half = 0; half < 2; half++) {
        if (half) __syncthreads();
        for (int cc = 0; cc < 5; cc++) {
            int c = t + cc * 512;
            int row = c >> 4, seg = c & 15;
            int src = half * 160 + row;
            bfrag v;
            if (src < C_) {
                v = *reinterpret_cast<const bfrag*>(kh + ((size_t)bh * C_ + src) * D_ + seg * 8);
            } else {
#pragma unroll
                for (int j = 0; j < 8; j++) v[j] = (__bf16)0.f;
            }
            *reinterpret_cast<bfrag*>(&sK[row * SLDA + seg * 8]) = v;
        }
        __syncthreads();
        if (!afLoaded) {
#pragma unroll
            for (int ks = 0; ks < 4; ks++)
                af[ks] = *reinterpret_cast<const bfrag*>(&sQ[(wm * 16 + l15) * SLDA + ks * 32 + quad * 8]);
            afLoaded = true;
        }
#pragma unroll
        for (int ks = 0; ks < 4; ks++) {
#pragma unroll
            for (int jj = 0; jj < 5; jj++) {
                int lr = (wn * 5 + jj) * 16 + l15;
                bfrag bf = *reinterpret_cast<const bfrag*>(&sK[lr * SLDA + ks * 32 + quad * 8]);
                acc[half * 5 + jj] = __builtin_amdgcn_mfma_f32_16x16x32_bf16(af[ks], bf, acc[half * 5 + jj], 0, 0, 0);
            }
        }
    }

    const float scale = 0.08838834764831845f;
    const float inv_sqrt2 = 0.7071067811865475f;
#pragma unroll
    for (int a = 0; a < 10; a++) {
        int gt = (a / 5) * 10 + wn * 5 + (a % 5);
        int col = gt * 16 + l15;
#pragma unroll
        for (int r = 0; r < 4; r++) {
            float v = acc[a][r];
            float ge = 0.5f * v * (1.0f + erff(v * inv_sqrt2));
            float s = ge * scale;
            if (col >= C_) s = -FLT_MAX;
            acc[a][r] = s;
        }
    }
    float mx[4];
#pragma unroll
    for (int r = 0; r < 4; r++) {
        float m = -FLT_MAX;
#pragma unroll
        for (int a = 0; a < 10; a++) m = fmaxf(m, acc[a][r]);
        for (int o = 1; o < 16; o <<= 1) m = fmaxf(m, __shfl_xor(m, o));
        mx[r] = m;
    }
    if (l15 == 0) {
#pragma unroll
        for (int r = 0; r < 4; r++) smax[wm * 16 + quad * 4 + r][wn] = mx[r];
    }
    __syncthreads();
    float sm[4];
#pragma unroll
    for (int r = 0; r < 4; r++) {
        int row = wm * 16 + quad * 4 + r;
        float m = fmaxf(smax[row][0], smax[row][1]);
        float s = 0.f;
#pragma unroll
        for (int a = 0; a < 10; a++) {
            float e = __expf(acc[a][r] - m);
            acc[a][r] = e;
            s += e;
        }
        for (int o = 1; o < 16; o <<= 1) s += __shfl_xor(s, o);
        sm[r] = s;
    }
    if (l15 == 0) {
#pragma unroll
        for (int r = 0; r < 4; r++) ssum[wm * 16 + quad * 4 + r][wn] = sm[r];
    }
    __syncthreads();

#pragma unroll
    for (int r = 0; r < 4; r++) {
        int row = wm * 16 + quad * 4 + r;
        float inv = 1.0f / (ssum[row][0] + ssum[row][1]);
        int grow = strip * 64 + row;
        float* ao = attnOut + ((size_t)bh * C_ + grow) * C_;
#pragma unroll
        for (int a = 0; a < 10; a++) {
            int gt = (a / 5) * 10 + wn * 5 + (a % 5);
            int col = gt * 16 + l15;
            float pv = acc[a][r] * inv;
            if (grow < C_ && col < C_) ao[col] = pv;
            sP[row * PLDA + col] = f2bf(pv);
        }
    }

    // ---- phase 2: PV ----
    f32x4 acc2[4];
#pragma unroll
    for (int i = 0; i < 4; i++) acc2[i] = (f32x4)(0.f);

    auto stageV = [&](int chunk) {
#pragma unroll
        for (int it = 0; it < 2; it++) {
            int g = t + it * 512;
            int d = g & 127;
            int oct = g >> 7;
            int ktl = oct >> 2, quad2 = oct & 3;
            int cb = chunk * 64 + ktl * 32 + quad2 * 8;
            const __bf16* vp = vh + ((size_t)bh * C_ + cb) * D_ + d;
            bfrag v;
            if (cb + 7 < C_) {
#pragma unroll
                for (int j = 0; j < 8; j++) v[j] = vp[(size_t)j * D_];
            } else {
#pragma unroll
                for (int j = 0; j < 8; j++) v[j] = (cb + j < C_) ? vp[(size_t)j * D_] : (__bf16)0.f;
            }
            *reinterpret_cast<bfrag*>(&sV[(((ktl * 8 + (d >> 4)) * 64) + quad2 * 16 + (d & 15)) * 8]) = v;
        }
    };

    stageV(0);
    __syncthreads();

    for (int chunk = 0; chunk < 5; chunk++) {
#pragma unroll
        for (int ktl = 0; ktl < 2; ktl++) {
            bfrag a = *reinterpret_cast<const bfrag*>(
                &sP[(wm * 16 + l15) * PLDA + chunk * 64 + ktl * 32 + quad * 8]);
#pragma unroll
            for (int ntl = 0; ntl < 4; ntl++) {
                int ntg = wn * 4 + ntl;
                bfrag b = *reinterpret_cast<const bfrag*>(&sV[(((ktl * 8 + ntg) * 64) + lane) * 8]);
                acc2[ntl] = __builtin_amdgcn_mfma_f32_16x16x32_bf16(a, b, acc2[ntl], 0, 0, 0);
            }
        }
        if (chunk < 4) {
            __syncthreads();
            stageV(chunk + 1);
            __syncthreads();
        }
    }

    int b = bh >> 3, h = bh & 7;
#pragma unroll
    for (int ntl = 0; ntl < 4; ntl++) {
        int d = wn * 64 + ntl * 16 + l15;
#pragma unroll
        for (int r = 0; r < 4; r++) {
            int c = strip * 64 + wm * 16 + quad * 4 + r;
            if (c < C_) {
                size_t oi = ((size_t)b * C_ + h * 39 + (c >> 3)) * N_ + ((c & 7) << 7) + d;
                ctx[oi] = f2bf(acc2[ntl][r]);
            }
        }
    }
}

// ---------------- L2 row norm (fp32 out), float4 -----------------------------
__global__ void norm_kernel(const float* __restrict__ out3, float* __restrict__ outp) {
    int r = blockIdx.x;
    const float* p = out3 + (size_t)r * N_;
    float4 f4 = *reinterpret_cast<const float4*>(p + threadIdx.x * 4);
    float sq = f4.x * f4.x + f4.y * f4.y + f4.z * f4.z + f4.w * f4.w;
    __shared__ float rq[256];
    rq[threadIdx.x] = sq; __syncthreads();
    for (int o = 128; o > 0; o >>= 1) {
        if (threadIdx.x < o) rq[threadIdx.x] += rq[threadIdx.x + o];
        __syncthreads();
    }
    float inv = 1.0f / fmaxf(sqrtf(rq[0]), 1e-12f);
    float4 o4 = { f4.x * inv, f4.y * inv, f4.z * inv, f4.w * inv };
    *reinterpret_cast<float4*>(outp + (size_t)r * N_ + threadIdx.x * 4) = o4;
}

// ---------------- host orchestration ----------------------------------------
extern "C" void kernel_launch(void* const* d_in, const int* in_sizes, int n_in,
                              void* d_out, int out_size, void* d_ws, size_t ws_size,
                              hipStream_t stream) {
    const float* x      = (const float*)d_in[0];
    const float* ln_q_g = (const float*)d_in[3];
    const float* ln_q_b = (const float*)d_in[4];
    const float* ln_k_g = (const float*)d_in[5];
    const float* ln_k_b = (const float*)d_in[6];
    const float* ln_v_g = (const float*)d_in[7];
    const float* ln_v_b = (const float*)d_in[8];
    const float* w_q    = (const float*)d_in[9];
    const float* w_k    = (const float*)d_in[10];
    const float* w_v    = (const float*)d_in[11];
    const float* w_proj = (const float*)d_in[12];
    const float* b_proj = (const float*)d_in[13];
    const float* dw0    = (const float*)d_in[14];
    const float* pw0    = (const float*)d_in[15];
    const float* gn_g   = (const float*)d_in[16];
    const float* gn_b   = (const float*)d_in[17];
    const float* dw1    = (const float*)d_in[18];
    const float* pw1    = (const float*)d_in[19];
    const float* dw2    = (const float*)d_in[20];
    const float* pw2    = (const float*)d_in[21];
    const float* bn0_g  = (const float*)d_in[22];
    const float* bn0_b  = (const float*)d_in[23];
    const float* bn0_m  = (const float*)d_in[24];
    const float* bn0_v  = (const float*)d_in[25];
    const float* bn1_g  = (const float*)d_in[26];
    const float* bn1_b  = (const float*)d_in[27];
    const float* bn1_m  = (const float*)d_in[28];
    const float* bn1_v  = (const float*)d_in[29];
    const float* bn2_g  = (const float*)d_in[30];
    const float* bn2_b  = (const float*)d_in[31];
    const float* bn2_m  = (const float*)d_in[32];
    const float* bn2_v  = (const float*)d_in[33];

    char* ws = (char*)d_ws;
    size_t off = 0;
    auto alloc = [&](size_t bytes) {
        void* p = ws + off;
        off = (off + bytes + 255) & ~(size_t)255;
        return p;
    };
    const size_t BF_BYTES = (size_t)BC_ * N_ * sizeof(bf16);
    const size_t T2_FLOATS = (size_t)B_ * SD_ * N_;
    bf16*  xn   = (bf16*)alloc(BF_BYTES);
    bf16*  qb   = (bf16*)alloc(BF_BYTES);
    bf16*  kb   = (bf16*)alloc(BF_BYTES);
    bf16*  vb   = (bf16*)alloc(BF_BYTES);
    float* tmp2 = (float*)alloc(3 * T2_FLOATS * sizeof(float));       // 38.3 MB
    float* gnst = (float*)alloc(2048);
    bf16*  wqkv = (bf16*)alloc((size_t)3 * N_ * N_ * sizeof(bf16));   // 6 MB
    float* bias3 = (float*)alloc((size_t)3 * N_ * sizeof(float));
    bf16*  wpb  = (bf16*)alloc((size_t)N_ * N_ * sizeof(bf16));       // 2 MB

    float* out_main = (float*)d_out;
    float* attn_out = out_main + (size_t)BC_ * N_;

    bf16* qh  = xn;
    bf16* kh  = (bf16*)out_main;
    bf16* vh  = kh + (size_t)BC_ * N_;
    bf16* ctx = vb;
    float* out3 = (float*)qb;
    float* r0 = tmp2, *r1 = tmp2 + T2_FLOATS, *r2 = tmp2 + 2 * T2_FLOATS;

    hipLaunchKernelGGL(wcvt_kernel, dim3(4096), dim3(256), 0, stream,
                       w_q, w_k, w_v, w_proj,
                       ln_q_g, ln_q_b, ln_k_g, ln_k_b, ln_v_g, ln_v_b,
                       wqkv, bias3, wpb);
    hipLaunchKernelGGL(ln_kernel, dim3(BC_), dim3(256), 0, stream, x, xn);
    hipLaunchKernelGGL((mfma_gemm_bw<false>), dim3(24 * 78), dim3(256), 0, stream,
                       xn, wqkv, bias3, 24, (void*)qb, (void*)kb, (void*)vb);

    hipLaunchKernelGGL(seg0_kernel, dim3(B_ * SD_, 3), dim3(256), 0, stream,
                       qb, kb, vb, qh, kh, vh, bn0_g, bn0_b, bn0_m, bn0_v);
    hipLaunchKernelGGL(dwpw_all_kernel, dim3(B_ * 16, 3, 3), dim3(512), 0, stream,
                       qb, kb, vb,
                       dw1, pw1, bn1_g, bn1_b, bn1_m, bn1_v,
                       dw2, pw2, bn2_g, bn2_b, bn2_m, bn2_v,
                       dw0, pw0,
                       qh, kh, vh, r0, r1, r2);
    hipLaunchKernelGGL(gn_stats_kernel, dim3(B_ * 2, 3), dim3(256), 0, stream,
                       r0, r1, r2, gnst);
    hipLaunchKernelGGL(gn_apply_kernel, dim3(B_ * SD_, 3), dim3(256), 0, stream,
                       r0, r1, r2, gnst, gn_g, gn_b, qh, kh, vh);

    hipLaunchKernelGGL(attn_av_kernel, dim3(5, BH_), dim3(512), 0, stream,
                       qh, kh, vh, attn_out, ctx);
    hipLaunchKernelGGL((mfma_gemm_bw<true>), dim3(8 * 78), dim3(256), 0, stream,
                       ctx, wpb, b_proj, 8, (void*)out3, (void*)out3, (void*)out3);
    hipLaunchKernelGGL(norm_kernel, dim3(BC_), dim3(256), 0, stream, out3, out_main);
}

// Round 18
// 548.046 us; speedup vs baseline: 1.1563x; 1.0230x over previous
//
#include <hip/hip_runtime.h>
#include <hip/hip_bf16.h>
#include <float.h>

typedef __hip_bfloat16 bf16;
typedef __attribute__((ext_vector_type(8))) __bf16 bfrag;   // MFMA A/B operand (4 VGPRs)
typedef __attribute__((ext_vector_type(4))) float f32x4;    // MFMA C/D operand

#define B_ 32
#define C_ 312
#define N_ 1024
#define H_ 8
#define D_ 128
#define SD_ 78
#define BC_ (B_ * C_)      // 9984
#define BH_ (B_ * H_)      // 256

__device__ __forceinline__ float bf2f(bf16 x) { return __bfloat162float(x); }
__device__ __forceinline__ bf16 f2bf(float x) { return __float2bfloat16(x); }
__device__ __forceinline__ float hswish(float x) {
    return x * fminf(fmaxf(x + 3.0f, 0.0f), 6.0f) * (1.0f / 6.0f);
}

__device__ __forceinline__ void gload_lds16(const void* g, void* l) {
    __builtin_amdgcn_global_load_lds(
        (const __attribute__((address_space(1))) void*)g,
        (__attribute__((address_space(3))) void*)l, 16, 0, 0);
}

// dwT bank-conflict-free addressing: [64 pos][128 c-slots], chunk XOR swizzle.
// Writes (pos stride 8 within a unit's k-loop) land 2 lanes/bank; reads use the
// same swizzle keyed on row=pos to fetch the contiguous 8-k chunk.
__device__ __forceinline__ int dwt_idx(int pos, int c) {
    return pos * 128 + ((((c >> 3) ^ (pos & 7) ^ ((pos >> 3) & 7)) * 8) | (c & 7));
}

// ---------------- LayerNorm (stats only; affine folded into W), float4 ------
__global__ void ln_kernel(const float* __restrict__ x, bf16* __restrict__ xn) {
    int r = blockIdx.x;
    int t = threadIdx.x;
    const float* xr = x + (size_t)r * N_;
    float4 v4 = *reinterpret_cast<const float4*>(xr + t * 4);
    float s = v4.x + v4.y + v4.z + v4.w;
    float sq = v4.x * v4.x + v4.y * v4.y + v4.z * v4.z + v4.w * v4.w;
    __shared__ float rs[256], rq[256];
    rs[t] = s; rq[t] = sq; __syncthreads();
    for (int o = 128; o > 0; o >>= 1) {
        if (t < o) { rs[t] += rs[t + o]; rq[t] += rq[t + o]; }
        __syncthreads();
    }
    float mu = rs[0] * (1.0f / N_);
    float var = rq[0] * (1.0f / N_) - mu * mu;
    float rstd = rsqrtf(var + 1e-5f);
    __bf16 o4[4] = { (__bf16)((v4.x - mu) * rstd), (__bf16)((v4.y - mu) * rstd),
                     (__bf16)((v4.z - mu) * rstd), (__bf16)((v4.w - mu) * rstd) };
    *reinterpret_cast<uint2*>(reinterpret_cast<__bf16*>(xn) + (size_t)r * N_ + t * 4) =
        *reinterpret_cast<const uint2*>(o4);
}

// ---- W preconvert: fold LN gamma into W (bf16), beta into bias row ---------
__global__ void wcvt_kernel(const float* __restrict__ wq, const float* __restrict__ wk,
                            const float* __restrict__ wv, const float* __restrict__ wp,
                            const float* __restrict__ gq, const float* __restrict__ bq,
                            const float* __restrict__ gk, const float* __restrict__ bk,
                            const float* __restrict__ gv, const float* __restrict__ bv_,
                            bf16* __restrict__ wqkv, float* __restrict__ bias3,
                            bf16* __restrict__ wpb) {
    int n = blockIdx.x;          // 0..4095
    int t = threadIdx.x;         // 256
    int k4 = t * 4;
    const float* src; const float* G = nullptr; const float* Bv = nullptr;
    if (n < 1024)      { src = wq + (size_t)n * N_;          G = gq; Bv = bq; }
    else if (n < 2048) { src = wk + (size_t)(n - 1024) * N_; G = gk; Bv = bk; }
    else if (n < 3072) { src = wv + (size_t)(n - 2048) * N_; G = gv; Bv = bv_; }
    else               { src = wp + (size_t)(n - 3072) * N_; }
    float4 w4 = *reinterpret_cast<const float4*>(src + k4);
    if (G) {
        __bf16 o[4] = { (__bf16)(w4.x * G[k4]),     (__bf16)(w4.y * G[k4 + 1]),
                        (__bf16)(w4.z * G[k4 + 2]), (__bf16)(w4.w * G[k4 + 3]) };
        *reinterpret_cast<uint2*>(wqkv + (size_t)n * N_ + k4) = *reinterpret_cast<const uint2*>(o);
        float s = w4.x * Bv[k4] + w4.y * Bv[k4 + 1] + w4.z * Bv[k4 + 2] + w4.w * Bv[k4 + 3];
        __shared__ float rs[256];
        rs[t] = s; __syncthreads();
        for (int o2 = 128; o2 > 0; o2 >>= 1) {
            if (t < o2) rs[t] += rs[t + o2];
            __syncthreads();
        }
        if (t == 0) bias3[n] = rs[0];
    } else {
        __bf16 o[4] = { (__bf16)w4.x, (__bf16)w4.y, (__bf16)w4.z, (__bf16)w4.w };
        *reinterpret_cast<uint2*>(wpb + (size_t)(n - 3072) * N_ + k4) = *reinterpret_cast<const uint2*>(o);
    }
}

// ---------------- MFMA GEMM v3: global_load_lds + XOR-swizzled LDS ----------
template <bool OUTF32>
__global__ __launch_bounds__(256) void mfma_gemm_bw(
        const bf16* __restrict__ A_,
        const bf16* __restrict__ Wb,
        const float* __restrict__ bias, int nTx,
        void* __restrict__ O0, void* __restrict__ O1, void* __restrict__ O2) {
    const int K = 1024, Nout = 1024;
    __shared__ __bf16 sA[128 * 64];
    __shared__ __bf16 sB[128 * 64];
    const __bf16* A = reinterpret_cast<const __bf16*>(A_);
    const __bf16* W = reinterpret_cast<const __bf16*>(Wb);

    int t = threadIdx.x;
    int lane = t & 63, wave = t >> 6;
    int wm = (wave >> 1) * 64, wn = (wave & 1) * 64;
    int quad = lane >> 4, l15 = lane & 15;

    int cpx = gridDim.x >> 3;
    int tile = (blockIdx.x & 7) * cpx + (blockIdx.x >> 3);
    int bx = tile % nTx, by = tile / nTx;
    int m0 = by * 128;
    int w0 = bx * 128;
    int which = bx >> 3;
    int n0 = (bx & 7) * 128;

    int rowLoc = wave * 8 + (lane >> 3);
    int c8s = (lane & 7) ^ (lane >> 3);
    const __bf16* gA = A + (size_t)(m0 + rowLoc) * K + c8s * 8;
    const __bf16* gW = W + (size_t)(w0 + rowLoc) * K + c8s * 8;

    f32x4 acc[4][4];
#pragma unroll
    for (int i = 0; i < 4; i++)
#pragma unroll
        for (int j = 0; j < 4; j++) acc[i][j] = (f32x4)(0.f);

    for (int kt = 0; kt < 16; kt++) {
        int k0 = kt * 64;
#pragma unroll
        for (int cc = 0; cc < 4; cc++) {
            gload_lds16(gA + (size_t)cc * 32 * K + k0, &sA[cc * 2048 + wave * 512]);
            gload_lds16(gW + (size_t)cc * 32 * K + k0, &sB[cc * 2048 + wave * 512]);
        }
        __syncthreads();
#pragma unroll
        for (int kk = 0; kk < 2; kk++) {
            bfrag af[4], bfr[4];
#pragma unroll
            for (int mt = 0; mt < 4; mt++) {
                int row = wm + mt * 16 + l15;
                af[mt] = *reinterpret_cast<const bfrag*>(
                    &sA[(row * 8 + ((kk * 4 + quad) ^ (row & 7))) * 8]);
            }
#pragma unroll
            for (int nt = 0; nt < 4; nt++) {
                int row = wn + nt * 16 + l15;
                bfr[nt] = *reinterpret_cast<const bfrag*>(
                    &sB[(row * 8 + ((kk * 4 + quad) ^ (row & 7))) * 8]);
            }
#pragma unroll
            for (int mt = 0; mt < 4; mt++)
#pragma unroll
                for (int nt = 0; nt < 4; nt++)
                    acc[mt][nt] = __builtin_amdgcn_mfma_f32_16x16x32_bf16(af[mt], bfr[nt], acc[mt][nt], 0, 0, 0);
        }
        __syncthreads();
    }
    void* Cout = which == 0 ? O0 : (which == 1 ? O1 : O2);
#pragma unroll
    for (int mt = 0; mt < 4; mt++) {
#pragma unroll
        for (int nt = 0; nt < 4; nt++) {
            int cloc = wn + nt * 16 + l15;
            float bb = bias ? bias[w0 + cloc] : 0.f;
            int col = n0 + cloc;
#pragma unroll
            for (int r = 0; r < 4; r++) {
                int row = m0 + wm + mt * 16 + quad * 4 + r;
                float v = acc[mt][nt][r] + bb;
                if (OUTF32) ((float*)Cout)[(size_t)row * Nout + col] = v;
                else        ((bf16*)Cout)[(size_t)row * Nout + col] = f2bf(v);
            }
        }
    }
}

// ---- fused depthwise(KS) + MFMA pointwise, v9 ------------------------------
// dwT: [64][128] chunk-XOR-swizzled (writes 2-way, reads ~4-way vs v8's 16-way)
// sWm: [80][104] (dword stride 52 -> rows spread across banks).
template <int KS, int MODE>
__device__ __forceinline__ void dwpw_impl(
        char* uMem, float* sWk, __bf16* dwT,
        const bf16* __restrict__ tin, int cOff,
        const float* __restrict__ dw, const float* __restrict__ pw,
        const float* __restrict__ g, const float* __restrict__ b,
        const float* __restrict__ m, const float* __restrict__ v,
        bf16* __restrict__ th, float* __restrict__ rawOut,
        int strip, int bi, int tid) {
    constexpr int WKP = ((KS * KS + 3) / 4) * 4;     // 28 / 12
    constexpr int NR  = KS + 1;                      // staged input rows
    __bf16* sIn = reinterpret_cast<__bf16*>(uMem);   // [78][NR][40]
    __bf16* sWm = reinterpret_cast<__bf16*>(uMem);   // [80][104] (after dw)
    const int P = KS / 2;

    // zero pads of sIn rows (uint2 = 4 bf16)
    for (int u = tid; u < SD_ * NR * 2; u += 512) {
        int rowi = u >> 1, side = u & 1;
        *reinterpret_cast<uint2*>(sIn + rowi * 40 + (side ? 36 : 0)) = make_uint2(0u, 0u);
    }
    // zero the whole dwT (covers K-padding and swizzle spill range)
    for (int u = tid; u < 64 * 128 / 8; u += 512) {
        *reinterpret_cast<uint4*>(dwT + u * 8) = make_uint4(0u, 0u, 0u, 0u);
    }
    // stage NR input rows (zero outside image): uint4 read -> 2x uint2 LDS
    const __bf16* tbase = reinterpret_cast<const __bf16*>(tin) + ((size_t)bi * C_ + cOff) * N_;
    for (int u = tid; u < SD_ * NR * 4; u += 512) {
        int c = u / (NR * 4);
        int rem = u - c * (NR * 4);
        int di = rem >> 2, cb = rem & 3;
        int ii = 2 * strip + di - P;
        uint4 val = make_uint4(0u, 0u, 0u, 0u);
        if (ii >= 0 && ii <= 31)
            val = *reinterpret_cast<const uint4*>(tbase + (size_t)c * N_ + ii * 32 + cb * 8);
        __bf16* dst = sIn + (c * NR + di) * 40 + 4 + cb * 8;
        *reinterpret_cast<uint2*>(dst)     = make_uint2(val.x, val.y);
        *reinterpret_cast<uint2*>(dst + 4) = make_uint2(val.z, val.w);
    }
    // stage dw weights
    for (int i = tid; i < SD_ * KS * KS; i += 512) {
        int c = i / (KS * KS), q = i - c * (KS * KS);
        sWk[c * WKP + q] = dw[i];
    }
    __syncthreads();

    // dw compute: unit = (c, row 0/1, 8-col group q8) -> dwT swizzled
    for (int u = tid; u < SD_ * 8; u += 512) {
        int c = u >> 3, grp = u & 7;
        int row = grp >> 2, q8 = (grp & 3) << 3;
        const __bf16* rbase = sIn + (size_t)(c * NR + row) * 40;
        __bf16 rowv[KS][16];
#pragma unroll
        for (int di = 0; di < KS; di++) {
            *reinterpret_cast<bfrag*>(&rowv[di][0]) = *reinterpret_cast<const bfrag*>(rbase + di * 40 + q8);
            *reinterpret_cast<bfrag*>(&rowv[di][8]) = *reinterpret_cast<const bfrag*>(rbase + di * 40 + q8 + 8);
        }
        float wreg[WKP];
#pragma unroll
        for (int qq = 0; qq < WKP / 4; qq++)
            *reinterpret_cast<float4*>(&wreg[qq * 4]) =
                *reinterpret_cast<const float4*>(&sWk[c * WKP + qq * 4]);
        float acc8[8];
#pragma unroll
        for (int k = 0; k < 8; k++) acc8[k] = 0.f;
#pragma unroll
        for (int di = 0; di < KS; di++) {
#pragma unroll
            for (int dj = 0; dj < KS; dj++) {
                float w = wreg[di * KS + dj];
#pragma unroll
                for (int k = 0; k < 8; k++)
                    acc8[k] += (float)rowv[di][k + dj - P + 4] * w;
            }
        }
#pragma unroll
        for (int k = 0; k < 8; k++)
            dwT[dwt_idx(row * 32 + q8 + k, c)] = (__bf16)acc8[k];
    }
    __syncthreads();

    // stage pw weights bf16 into sWm [80][104] (o>=78 or c>=78 zero)
    for (int u = tid; u < 80 * 104; u += 512) {
        int o = u / 104, c = u - o * 104;
        float val = (o < SD_ && c < SD_) ? pw[o * SD_ + c] : 0.f;
        sWm[u] = (__bf16)val;
    }
    __syncthreads();

    // MFMA pw: wave w: n-tile = w&3 (16 pos), m-set = (w>>2)? {3,4} : {0,1,2}
    int lane = tid & 63, wave = tid >> 6;
    int quad = lane >> 4, l15 = lane & 15;
    int wn = wave & 3, mh = wave >> 2;
    int mt0 = mh ? 3 : 0;
    int mcnt = mh ? 2 : 3;
    f32x4 acc[3];
#pragma unroll
    for (int i = 0; i < 3; i++) acc[i] = (f32x4)(0.f);
#pragma unroll
    for (int kk = 0; kk < 3; kk++) {
        int prow = wn * 16 + l15;
        int ch = (kk * 4 + quad) ^ (prow & 7) ^ ((prow >> 3) & 7);
        bfrag bv = *reinterpret_cast<const bfrag*>(dwT + prow * 128 + ch * 8);
#pragma unroll
        for (int mi = 0; mi < 3; mi++) {
            if (mi < mcnt) {
                bfrag av = *reinterpret_cast<const bfrag*>(sWm + ((mt0 + mi) * 16 + l15) * 104 + kk * 32 + quad * 8);
                acc[mi] = __builtin_amdgcn_mfma_f32_16x16x32_bf16(av, bv, acc[mi], 0, 0, 0);
            }
        }
    }
    // epilogue: o = (mt0+mi)*16 + quad*4 + r, pos = wn*16 + l15
    int n = strip * 64 + wn * 16 + l15;
    if (MODE == 0) {
        bf16* base = th + (size_t)bi * H_ * C_ * D_;
#pragma unroll
        for (int mi = 0; mi < 3; mi++) {
            if (mi < mcnt) {
#pragma unroll
                for (int r = 0; r < 4; r++) {
                    int o = (mt0 + mi) * 16 + quad * 4 + r;
                    if (o < SD_) {
                        float inv = g[o] * rsqrtf(v[o] + 1e-5f);
                        float y = hswish((acc[mi][r] - m[o]) * inv + b[o]);
                        base[((n >> 7) * C_ + cOff + o) * D_ + (n & 127)] = f2bf(y);
                    }
                }
            }
        }
    } else {
        float* opr = rawOut + (size_t)bi * SD_ * N_;
#pragma unroll
        for (int mi = 0; mi < 3; mi++) {
            if (mi < mcnt) {
#pragma unroll
                for (int r = 0; r < 4; r++) {
                    int o = (mt0 + mi) * 16 + quad * 4 + r;
                    if (o < SD_) opr[(size_t)o * N_ + n] = acc[mi][r];
                }
            }
        }
    }
}

// ---- all three dw+pw branches + seg0 in ONE launch --------------------------
// grid (B*16, 3 tensors, 4 branches), 512 threads. Branches write disjoint
// outputs (th cols 0..77 / 78..155 / 156..233 / tmp2).
// LDS: sIn 37440 (union sWm 33280) + sWk 8736 + dwT 16384 = 62560 B -> 2/CU.
__global__ __launch_bounds__(512) void dwpw_all_kernel(
        const bf16* __restrict__ t0, const bf16* __restrict__ t1,
        const bf16* __restrict__ t2,
        const float* __restrict__ dw1, const float* __restrict__ pw1,
        const float* __restrict__ g1, const float* __restrict__ b1,
        const float* __restrict__ m1, const float* __restrict__ v1,
        const float* __restrict__ dw2, const float* __restrict__ pw2,
        const float* __restrict__ g2, const float* __restrict__ b2,
        const float* __restrict__ m2, const float* __restrict__ v2,
        const float* __restrict__ dw0, const float* __restrict__ pw0,
        const float* __restrict__ g0, const float* __restrict__ b0,
        const float* __restrict__ m0, const float* __restrict__ v0,
        bf16* __restrict__ h0, bf16* __restrict__ h1, bf16* __restrict__ h2,
        float* __restrict__ r0_, float* __restrict__ r1_, float* __restrict__ r2_) {
    __shared__ __align__(16) char uMem[SD_ * 6 * 40 * sizeof(__bf16)];  // 37440 B
    __shared__ __align__(16) float sWk[SD_ * 28];                       //  8736 B
    __shared__ __align__(16) __bf16 dwT[64 * 128];                      // 16384 B

    int ti = blockIdx.y;
    const bf16* tin = ti == 0 ? t0 : (ti == 1 ? t1 : t2);
    bf16* th = ti == 0 ? h0 : (ti == 1 ? h1 : h2);
    float* rawOut = ti == 0 ? r0_ : (ti == 1 ? r1_ : r2_);
    int strip = blockIdx.x & 15;      // 16 strips of 2 rows (64 positions)
    int bi = blockIdx.x >> 4;         // batch
    int tid = threadIdx.x;
    int branch = blockIdx.z;

    if (branch == 3) {
        // seg0: BN+hswish on raw rows, 64 positions, all 78 channels
        const __bf16* tb = reinterpret_cast<const __bf16*>(tin) + (size_t)bi * C_ * N_;
        __bf16* base = reinterpret_cast<__bf16*>(th) + (size_t)bi * H_ * C_ * D_;
        for (int u = tid; u < SD_ * 16; u += 512) {
            int c = u >> 4, p4 = u & 15;
            int n = strip * 64 + p4 * 4;
            uint2 in2 = *reinterpret_cast<const uint2*>(tb + (size_t)c * N_ + n);
            const __bf16* iv = reinterpret_cast<const __bf16*>(&in2);
            float inv = g0[c] * rsqrtf(v0[c] + 1e-5f);
            float mm = m0[c], bb = b0[c];
            __bf16 o4[4];
#pragma unroll
            for (int j = 0; j < 4; j++)
                o4[j] = (__bf16)hswish(((float)iv[j] - mm) * inv + bb);
            *reinterpret_cast<uint2*>(&base[((n >> 7) * C_ + c) * D_ + (n & 127)]) =
                *reinterpret_cast<const uint2*>(o4);
        }
        return;
    }

    if (branch == 0) {
        dwpw_impl<3, 0>(uMem, sWk, dwT, tin, SD_, dw1, pw1, g1, b1, m1, v1,
                        th, (float*)nullptr, strip, bi, tid);
    } else if (branch == 1) {
        dwpw_impl<5, 0>(uMem, sWk, dwT, tin, 2 * SD_, dw2, pw2, g2, b2, m2, v2,
                        th, (float*)nullptr, strip, bi, tid);
    } else {
        dwpw_impl<3, 1>(uMem, sWk, dwT, tin, 3 * SD_, dw0, pw0,
                        (const float*)nullptr, (const float*)nullptr,
                        (const float*)nullptr, (const float*)nullptr,
                        (bf16*)nullptr, rawOut, strip, bi, tid);
    }
}

// grid (64, 3): stats[ti*128 + bg*2 .. +1]
__global__ void gn_stats_kernel(const float* __restrict__ r0_, const float* __restrict__ r1_,
                                const float* __restrict__ r2_, float* __restrict__ stats) {
    int ti = blockIdx.y;
    const float* tmp2 = ti == 0 ? r0_ : (ti == 1 ? r1_ : r2_);
    int bg = blockIdx.x;
    int bi = bg >> 1, grp = bg & 1;
    const float* p = tmp2 + (size_t)bi * SD_ * N_ + (size_t)grp * 39 * N_;
    float s = 0.f, sq = 0.f;
    const int TOT = 39 * N_;
    for (int i = threadIdx.x * 4; i < TOT; i += 1024) {
        float4 f4 = *reinterpret_cast<const float4*>(p + i);
        s += f4.x + f4.y + f4.z + f4.w;
        sq += f4.x * f4.x + f4.y * f4.y + f4.z * f4.z + f4.w * f4.w;
    }
    __shared__ float rs[256], rq[256];
    rs[threadIdx.x] = s; rq[threadIdx.x] = sq; __syncthreads();
    for (int o = 128; o > 0; o >>= 1) {
        if (threadIdx.x < o) { rs[threadIdx.x] += rs[threadIdx.x + o]; rq[threadIdx.x] += rq[threadIdx.x + o]; }
        __syncthreads();
    }
    if (threadIdx.x == 0) {
        float mu = rs[0] / (float)TOT;
        float var = rq[0] / (float)TOT - mu * mu;
        stats[ti * 128 + bg * 2] = mu;
        stats[ti * 128 + bg * 2 + 1] = rsqrtf(var + 1e-5f);
    }
}

// grid (2496, 3)
__global__ void gn_apply_kernel(const float* __restrict__ r0_, const float* __restrict__ r1_,
                                const float* __restrict__ r2_, const float* __restrict__ stats,
                                const float* __restrict__ gg, const float* __restrict__ gb,
                                bf16* __restrict__ h0, bf16* __restrict__ h1,
                                bf16* __restrict__ h2) {
    int ti = blockIdx.y;
    const float* tmp2 = ti == 0 ? r0_ : (ti == 1 ? r1_ : r2_);
    bf16* th = ti == 0 ? h0 : (ti == 1 ? h1 : h2);
    int bc = blockIdx.x;
    int bi = bc / SD_, c = bc % SD_;
    int grp = c / 39;
    float mu = stats[ti * 128 + (bi * 2 + grp) * 2];
    float rstd = stats[ti * 128 + (bi * 2 + grp) * 2 + 1];
    float sc = gg[c] * rstd;
    float of = gb[c] - mu * sc;
    const float* p = tmp2 + ((size_t)bi * SD_ + c) * N_;
    __bf16* base = reinterpret_cast<__bf16*>(th) + (size_t)bi * H_ * C_ * D_;
    int n = threadIdx.x * 4;
    float4 f4 = *reinterpret_cast<const float4*>(p + n);
    __bf16 o4[4] = { (__bf16)hswish(f4.x * sc + of), (__bf16)hswish(f4.y * sc + of),
                     (__bf16)hswish(f4.z * sc + of), (__bf16)hswish(f4.w * sc + of) };
    *reinterpret_cast<uint2*>(&base[((n >> 7) * C_ + 234 + c) * D_ + (n & 127)]) =
        *reinterpret_cast<const uint2*>(o4);
}

// ---- FUSED attn: scores + GELU + softmax + attn-out + PV -> ctx ------------
#define SLDA 136
#define PLDA 328
__global__ __launch_bounds__(512, 4) void attn_av_kernel(
        const bf16* __restrict__ qh_, const bf16* __restrict__ kh_,
        const bf16* __restrict__ vh_,
        float* __restrict__ attnOut, bf16* __restrict__ ctx) {
    __shared__ __align__(16) char uni[60928];
    __shared__ float smax[64][2];
    __shared__ float ssum[64][2];
    __bf16* sQ = reinterpret_cast<__bf16*>(uni);            // [64][SLDA]
    __bf16* sK = reinterpret_cast<__bf16*>(uni + 17408);    // [160][SLDA]
    __bf16* sP = reinterpret_cast<__bf16*>(uni);            // [64][PLDA]
    __bf16* sV = reinterpret_cast<__bf16*>(uni + 41984);    // [2][8][64][8]
    const __bf16* qh = reinterpret_cast<const __bf16*>(qh_);
    const __bf16* kh = reinterpret_cast<const __bf16*>(kh_);
    const __bf16* vh = reinterpret_cast<const __bf16*>(vh_);

    int strip = blockIdx.x;
    int bh = blockIdx.y;
    int t = threadIdx.x;
    int lane = t & 63, wave = t >> 6;
    int quad = lane >> 4, l15 = lane & 15;
    int wm = wave >> 1;
    int wn = wave & 1;

#pragma unroll
    for (int cc = 0; cc < 2; cc++) {
        int c = t + cc * 512;
        int row = c >> 4, seg = c & 15;
        int src = strip * 64 + row; if (src > 311) src = 311;
        bfrag v = *reinterpret_cast<const bfrag*>(qh + ((size_t)bh * C_ + src) * D_ + seg * 8);
        *reinterpret_cast<bfrag*>(&sQ[row * SLDA + seg * 8]) = v;
    }

    f32x4 acc[10];
#pragma unroll
    for (int i = 0; i < 10; i++) acc[i] = (f32x4)(0.f);

    bfrag af[4];
    bool afLoaded = false;

    for (int half = 0; half < 2; half++) {
        if (half) __syncthreads();
        for (int cc = 0; cc < 5; cc++) {
            int c = t + cc * 512;
            int row = c >> 4, seg = c & 15;
            int src = half * 160 + row;
            bfrag v;
            if (src < C_) {
                v = *reinterpret_cast<const bfrag*>(kh + ((size_t)bh * C_ + src) * D_ + seg * 8);
            } else {
#pragma unroll
                for (int j = 0; j < 8; j++) v[j] = (__bf16)0.f;
            }
            *reinterpret_cast<bfrag*>(&sK[row * SLDA + seg * 8]) = v;
        }
        __syncthreads();
        if (!afLoaded) {
#pragma unroll
            for (int ks = 0; ks < 4; ks++)
                af[ks] = *reinterpret_cast<const bfrag*>(&sQ[(wm * 16 + l15) * SLDA + ks * 32 + quad * 8]);
            afLoaded = true;
        }
#pragma unroll
        for (int ks = 0; ks < 4; ks++) {
#pragma unroll
            for (int jj = 0; jj < 5; jj++) {
                int lr = (wn * 5 + jj) * 16 + l15;
                bfrag bf = *reinterpret_cast<const bfrag*>(&sK[lr * SLDA + ks * 32 + quad * 8]);
                acc[half * 5 + jj] = __builtin_amdgcn_mfma_f32_16x16x32_bf16(af[ks], bf, acc[half * 5 + jj], 0, 0, 0);
            }
        }
    }

    const float scale = 0.08838834764831845f;
    const float inv_sqrt2 = 0.7071067811865475f;
#pragma unroll
    for (int a = 0; a < 10; a++) {
        int gt = (a / 5) * 10 + wn * 5 + (a % 5);
        int col = gt * 16 + l15;
#pragma unroll
        for (int r = 0; r < 4; r++) {
            float v = acc[a][r];
            float ge = 0.5f * v * (1.0f + erff(v * inv_sqrt2));
            float s = ge * scale;
            if (col >= C_) s = -FLT_MAX;
            acc[a][r] = s;
        }
    }
    float mx[4];
#pragma unroll
    for (int r = 0; r < 4; r++) {
        float m = -FLT_MAX;
#pragma unroll
        for (int a = 0; a < 10; a++) m = fmaxf(m, acc[a][r]);
        for (int o = 1; o < 16; o <<= 1) m = fmaxf(m, __shfl_xor(m, o));
        mx[r] = m;
    }
    if (l15 == 0) {
#pragma unroll
        for (int r = 0; r < 4; r++) smax[wm * 16 + quad * 4 + r][wn] = mx[r];
    }
    __syncthreads();
    float sm[4];
#pragma unroll
    for (int r = 0; r < 4; r++) {
        int row = wm * 16 + quad * 4 + r;
        float m = fmaxf(smax[row][0], smax[row][1]);
        float s = 0.f;
#pragma unroll
        for (int a = 0; a < 10; a++) {
            float e = __expf(acc[a][r] - m);
            acc[a][r] = e;
            s += e;
        }
        for (int o = 1; o < 16; o <<= 1) s += __shfl_xor(s, o);
        sm[r] = s;
    }
    if (l15 == 0) {
#pragma unroll
        for (int r = 0; r < 4; r++) ssum[wm * 16 + quad * 4 + r][wn] = sm[r];
    }
    __syncthreads();

#pragma unroll
    for (int r = 0; r < 4; r++) {
        int row = wm * 16 + quad * 4 + r;
        float inv = 1.0f / (ssum[row][0] + ssum[row][1]);
        int grow = strip * 64 + row;
        float* ao = attnOut + ((size_t)bh * C_ + grow) * C_;
#pragma unroll
        for (int a = 0; a < 10; a++) {
            int gt = (a / 5) * 10 + wn * 5 + (a % 5);
            int col = gt * 16 + l15;
            float pv = acc[a][r] * inv;
            if (grow < C_ && col < C_) ao[col] = pv;
            sP[row * PLDA + col] = f2bf(pv);
        }
    }

    // ---- phase 2: PV ----
    f32x4 acc2[4];
#pragma unroll
    for (int i = 0; i < 4; i++) acc2[i] = (f32x4)(0.f);

    auto stageV = [&](int chunk) {
#pragma unroll
        for (int it = 0; it < 2; it++) {
            int g = t + it * 512;
            int d = g & 127;
            int oct = g >> 7;
            int ktl = oct >> 2, quad2 = oct & 3;
            int cb = chunk * 64 + ktl * 32 + quad2 * 8;
            const __bf16* vp = vh + ((size_t)bh * C_ + cb) * D_ + d;
            bfrag v;
            if (cb + 7 < C_) {
#pragma unroll
                for (int j = 0; j < 8; j++) v[j] = vp[(size_t)j * D_];
            } else {
#pragma unroll
                for (int j = 0; j < 8; j++) v[j] = (cb + j < C_) ? vp[(size_t)j * D_] : (__bf16)0.f;
            }
            *reinterpret_cast<bfrag*>(&sV[(((ktl * 8 + (d >> 4)) * 64) + quad2 * 16 + (d & 15)) * 8]) = v;
        }
    };

    stageV(0);
    __syncthreads();

    for (int chunk = 0; chunk < 5; chunk++) {
#pragma unroll
        for (int ktl = 0; ktl < 2; ktl++) {
            bfrag a = *reinterpret_cast<const bfrag*>(
                &sP[(wm * 16 + l15) * PLDA + chunk * 64 + ktl * 32 + quad * 8]);
#pragma unroll
            for (int ntl = 0; ntl < 4; ntl++) {
                int ntg = wn * 4 + ntl;
                bfrag b = *reinterpret_cast<const bfrag*>(&sV[(((ktl * 8 + ntg) * 64) + lane) * 8]);
                acc2[ntl] = __builtin_amdgcn_mfma_f32_16x16x32_bf16(a, b, acc2[ntl], 0, 0, 0);
            }
        }
        if (chunk < 4) {
            __syncthreads();
            stageV(chunk + 1);
            __syncthreads();
        }
    }

    int b = bh >> 3, h = bh & 7;
#pragma unroll
    for (int ntl = 0; ntl < 4; ntl++) {
        int d = wn * 64 + ntl * 16 + l15;
#pragma unroll
        for (int r = 0; r < 4; r++) {
            int c = strip * 64 + wm * 16 + quad * 4 + r;
            if (c < C_) {
                size_t oi = ((size_t)b * C_ + h * 39 + (c >> 3)) * N_ + ((c & 7) << 7) + d;
                ctx[oi] = f2bf(acc2[ntl][r]);
            }
        }
    }
}

// ---------------- L2 row norm (fp32 out), float4 -----------------------------
__global__ void norm_kernel(const float* __restrict__ out3, float* __restrict__ outp) {
    int r = blockIdx.x;
    const float* p = out3 + (size_t)r * N_;
    float4 f4 = *reinterpret_cast<const float4*>(p + threadIdx.x * 4);
    float sq = f4.x * f4.x + f4.y * f4.y + f4.z * f4.z + f4.w * f4.w;
    __shared__ float rq[256];
    rq[threadIdx.x] = sq; __syncthreads();
    for (int o = 128; o > 0; o >>= 1) {
        if (threadIdx.x < o) rq[threadIdx.x] += rq[threadIdx.x + o];
        __syncthreads();
    }
    float inv = 1.0f / fmaxf(sqrtf(rq[0]), 1e-12f);
    float4 o4 = { f4.x * inv, f4.y * inv, f4.z * inv, f4.w * inv };
    *reinterpret_cast<float4*>(outp + (size_t)r * N_ + threadIdx.x * 4) = o4;
}

// ---------------- host orchestration ----------------------------------------
extern "C" void kernel_launch(void* const* d_in, const int* in_sizes, int n_in,
                              void* d_out, int out_size, void* d_ws, size_t ws_size,
                              hipStream_t stream) {
    const float* x      = (const float*)d_in[0];
    const float* ln_q_g = (const float*)d_in[3];
    const float* ln_q_b = (const float*)d_in[4];
    const float* ln_k_g = (const float*)d_in[5];
    const float* ln_k_b = (const float*)d_in[6];
    const float* ln_v_g = (const float*)d_in[7];
    const float* ln_v_b = (const float*)d_in[8];
    const float* w_q    = (const float*)d_in[9];
    const float* w_k    = (const float*)d_in[10];
    const float* w_v    = (const float*)d_in[11];
    const float* w_proj = (const float*)d_in[12];
    const float* b_proj = (const float*)d_in[13];
    const float* dw0    = (const float*)d_in[14];
    const float* pw0    = (const float*)d_in[15];
    const float* gn_g   = (const float*)d_in[16];
    const float* gn_b   = (const float*)d_in[17];
    const float* dw1    = (const float*)d_in[18];
    const float* pw1    = (const float*)d_in[19];
    const float* dw2    = (const float*)d_in[20];
    const float* pw2    = (const float*)d_in[21];
    const float* bn0_g  = (const float*)d_in[22];
    const float* bn0_b  = (const float*)d_in[23];
    const float* bn0_m  = (const float*)d_in[24];
    const float* bn0_v  = (const float*)d_in[25];
    const float* bn1_g  = (const float*)d_in[26];
    const float* bn1_b  = (const float*)d_in[27];
    const float* bn1_m  = (const float*)d_in[28];
    const float* bn1_v  = (const float*)d_in[29];
    const float* bn2_g  = (const float*)d_in[30];
    const float* bn2_b  = (const float*)d_in[31];
    const float* bn2_m  = (const float*)d_in[32];
    const float* bn2_v  = (const float*)d_in[33];

    char* ws = (char*)d_ws;
    size_t off = 0;
    auto alloc = [&](size_t bytes) {
        void* p = ws + off;
        off = (off + bytes + 255) & ~(size_t)255;
        return p;
    };
    const size_t BF_BYTES = (size_t)BC_ * N_ * sizeof(bf16);
    const size_t T2_FLOATS = (size_t)B_ * SD_ * N_;
    bf16*  xn   = (bf16*)alloc(BF_BYTES);
    bf16*  qb   = (bf16*)alloc(BF_BYTES);
    bf16*  kb   = (bf16*)alloc(BF_BYTES);
    bf16*  vb   = (bf16*)alloc(BF_BYTES);
    float* tmp2 = (float*)alloc(3 * T2_FLOATS * sizeof(float));       // 38.3 MB
    float* gnst = (float*)alloc(2048);
    bf16*  wqkv = (bf16*)alloc((size_t)3 * N_ * N_ * sizeof(bf16));   // 6 MB
    float* bias3 = (float*)alloc((size_t)3 * N_ * sizeof(float));
    bf16*  wpb  = (bf16*)alloc((size_t)N_ * N_ * sizeof(bf16));       // 2 MB

    float* out_main = (float*)d_out;
    float* attn_out = out_main + (size_t)BC_ * N_;

    bf16* qh  = xn;
    bf16* kh  = (bf16*)out_main;
    bf16* vh  = kh + (size_t)BC_ * N_;
    bf16* ctx = vb;
    float* out3 = (float*)qb;
    float* r0 = tmp2, *r1 = tmp2 + T2_FLOATS, *r2 = tmp2 + 2 * T2_FLOATS;

    hipLaunchKernelGGL(wcvt_kernel, dim3(4096), dim3(256), 0, stream,
                       w_q, w_k, w_v, w_proj,
                       ln_q_g, ln_q_b, ln_k_g, ln_k_b, ln_v_g, ln_v_b,
                       wqkv, bias3, wpb);
    hipLaunchKernelGGL(ln_kernel, dim3(BC_), dim3(256), 0, stream, x, xn);
    hipLaunchKernelGGL((mfma_gemm_bw<false>), dim3(24 * 78), dim3(256), 0, stream,
                       xn, wqkv, bias3, 24, (void*)qb, (void*)kb, (void*)vb);

    hipLaunchKernelGGL(dwpw_all_kernel, dim3(B_ * 16, 3, 4), dim3(512), 0, stream,
                       qb, kb, vb,
                       dw1, pw1, bn1_g, bn1_b, bn1_m, bn1_v,
                       dw2, pw2, bn2_g, bn2_b, bn2_m, bn2_v,
                       dw0, pw0, bn0_g, bn0_b, bn0_m, bn0_v,
                       qh, kh, vh, r0, r1, r2);
    hipLaunchKernelGGL(gn_stats_kernel, dim3(B_ * 2, 3), dim3(256), 0, stream,
                       r0, r1, r2, gnst);
    hipLaunchKernelGGL(gn_apply_kernel, dim3(B_ * SD_, 3), dim3(256), 0, stream,
                       r0, r1, r2, gnst, gn_g, gn_b, qh, kh, vh);

    hipLaunchKernelGGL(attn_av_kernel, dim3(5, BH_), dim3(512), 0, stream,
                       qh, kh, vh, attn_out, ctx);
    hipLaunchKernelGGL((mfma_gemm_bw<true>), dim3(8 * 78), dim3(256), 0, stream,
                       ctx, wpb, b_proj, 8, (void*)out3, (void*)out3, (void*)out3);
    hipLaunchKernelGGL(norm_kernel, dim3(BC_), dim3(256), 0, stream, out3, out_main);
}

// Round 19
// 539.760 us; speedup vs baseline: 1.1740x; 1.0154x over previous
//
#include <hip/hip_runtime.h>
#include <hip/hip_bf16.h>
#include <float.h>

typedef __hip_bfloat16 bf16;
typedef __attribute__((ext_vector_type(8))) __bf16 bfrag;   // MFMA A/B operand (4 VGPRs)
typedef __attribute__((ext_vector_type(4))) float f32x4;    // MFMA C/D operand

#define B_ 32
#define C_ 312
#define N_ 1024
#define H_ 8
#define D_ 128
#define SD_ 78
#define BC_ (B_ * C_)      // 9984
#define BH_ (B_ * H_)      // 256

__device__ __forceinline__ float bf2f(bf16 x) { return __bfloat162float(x); }
__device__ __forceinline__ bf16 f2bf(float x) { return __float2bfloat16(x); }
__device__ __forceinline__ float hswish(float x) {
    return x * fminf(fmaxf(x + 3.0f, 0.0f), 6.0f) * (1.0f / 6.0f);
}

__device__ __forceinline__ void gload_lds16(const void* g, void* l) {
    __builtin_amdgcn_global_load_lds(
        (const __attribute__((address_space(1))) void*)g,
        (__attribute__((address_space(3))) void*)l, 16, 0, 0);
}

// dwT bank-conflict-free addressing: [64 pos][128 c-slots], chunk XOR swizzle.
__device__ __forceinline__ int dwt_idx(int pos, int c) {
    return pos * 128 + ((((c >> 3) ^ (pos & 7) ^ ((pos >> 3) & 7)) * 8) | (c & 7));
}

// ---------------- LayerNorm (stats only; affine folded into W), float4 ------
__global__ void ln_kernel(const float* __restrict__ x, bf16* __restrict__ xn) {
    int r = blockIdx.x;
    int t = threadIdx.x;
    const float* xr = x + (size_t)r * N_;
    float4 v4 = *reinterpret_cast<const float4*>(xr + t * 4);
    float s = v4.x + v4.y + v4.z + v4.w;
    float sq = v4.x * v4.x + v4.y * v4.y + v4.z * v4.z + v4.w * v4.w;
    __shared__ float rs[256], rq[256];
    rs[t] = s; rq[t] = sq; __syncthreads();
    for (int o = 128; o > 0; o >>= 1) {
        if (t < o) { rs[t] += rs[t + o]; rq[t] += rq[t + o]; }
        __syncthreads();
    }
    float mu = rs[0] * (1.0f / N_);
    float var = rq[0] * (1.0f / N_) - mu * mu;
    float rstd = rsqrtf(var + 1e-5f);
    __bf16 o4[4] = { (__bf16)((v4.x - mu) * rstd), (__bf16)((v4.y - mu) * rstd),
                     (__bf16)((v4.z - mu) * rstd), (__bf16)((v4.w - mu) * rstd) };
    *reinterpret_cast<uint2*>(reinterpret_cast<__bf16*>(xn) + (size_t)r * N_ + t * 4) =
        *reinterpret_cast<const uint2*>(o4);
}

// ---- W preconvert: fold LN gamma into W (bf16), beta into bias row ---------
__global__ void wcvt_kernel(const float* __restrict__ wq, const float* __restrict__ wk,
                            const float* __restrict__ wv, const float* __restrict__ wp,
                            const float* __restrict__ gq, const float* __restrict__ bq,
                            const float* __restrict__ gk, const float* __restrict__ bk,
                            const float* __restrict__ gv, const float* __restrict__ bv_,
                            bf16* __restrict__ wqkv, float* __restrict__ bias3,
                            bf16* __restrict__ wpb) {
    int n = blockIdx.x;          // 0..4095
    int t = threadIdx.x;         // 256
    int k4 = t * 4;
    const float* src; const float* G = nullptr; const float* Bv = nullptr;
    if (n < 1024)      { src = wq + (size_t)n * N_;          G = gq; Bv = bq; }
    else if (n < 2048) { src = wk + (size_t)(n - 1024) * N_; G = gk; Bv = bk; }
    else if (n < 3072) { src = wv + (size_t)(n - 2048) * N_; G = gv; Bv = bv_; }
    else               { src = wp + (size_t)(n - 3072) * N_; }
    float4 w4 = *reinterpret_cast<const float4*>(src + k4);
    if (G) {
        __bf16 o[4] = { (__bf16)(w4.x * G[k4]),     (__bf16)(w4.y * G[k4 + 1]),
                        (__bf16)(w4.z * G[k4 + 2]), (__bf16)(w4.w * G[k4 + 3]) };
        *reinterpret_cast<uint2*>(wqkv + (size_t)n * N_ + k4) = *reinterpret_cast<const uint2*>(o);
        float s = w4.x * Bv[k4] + w4.y * Bv[k4 + 1] + w4.z * Bv[k4 + 2] + w4.w * Bv[k4 + 3];
        __shared__ float rs[256];
        rs[t] = s; __syncthreads();
        for (int o2 = 128; o2 > 0; o2 >>= 1) {
            if (t < o2) rs[t] += rs[t + o2];
            __syncthreads();
        }
        if (t == 0) bias3[n] = rs[0];
    } else {
        __bf16 o[4] = { (__bf16)w4.x, (__bf16)w4.y, (__bf16)w4.z, (__bf16)w4.w };
        *reinterpret_cast<uint2*>(wpb + (size_t)(n - 3072) * N_ + k4) = *reinterpret_cast<const uint2*>(o);
    }
}

// ---------------- MFMA GEMM v3: global_load_lds + XOR-swizzled LDS ----------
template <bool OUTF32>
__global__ __launch_bounds__(256) void mfma_gemm_bw(
        const bf16* __restrict__ A_,
        const bf16* __restrict__ Wb,
        const float* __restrict__ bias, int nTx,
        void* __restrict__ O0, void* __restrict__ O1, void* __restrict__ O2) {
    const int K = 1024, Nout = 1024;
    __shared__ __bf16 sA[128 * 64];
    __shared__ __bf16 sB[128 * 64];
    const __bf16* A = reinterpret_cast<const __bf16*>(A_);
    const __bf16* W = reinterpret_cast<const __bf16*>(Wb);

    int t = threadIdx.x;
    int lane = t & 63, wave = t >> 6;
    int wm = (wave >> 1) * 64, wn = (wave & 1) * 64;
    int quad = lane >> 4, l15 = lane & 15;

    int cpx = gridDim.x >> 3;
    int tile = (blockIdx.x & 7) * cpx + (blockIdx.x >> 3);
    int bx = tile % nTx, by = tile / nTx;
    int m0 = by * 128;
    int w0 = bx * 128;
    int which = bx >> 3;
    int n0 = (bx & 7) * 128;

    int rowLoc = wave * 8 + (lane >> 3);
    int c8s = (lane & 7) ^ (lane >> 3);
    const __bf16* gA = A + (size_t)(m0 + rowLoc) * K + c8s * 8;
    const __bf16* gW = W + (size_t)(w0 + rowLoc) * K + c8s * 8;

    f32x4 acc[4][4];
#pragma unroll
    for (int i = 0; i < 4; i++)
#pragma unroll
        for (int j = 0; j < 4; j++) acc[i][j] = (f32x4)(0.f);

    for (int kt = 0; kt < 16; kt++) {
        int k0 = kt * 64;
#pragma unroll
        for (int cc = 0; cc < 4; cc++) {
            gload_lds16(gA + (size_t)cc * 32 * K + k0, &sA[cc * 2048 + wave * 512]);
            gload_lds16(gW + (size_t)cc * 32 * K + k0, &sB[cc * 2048 + wave * 512]);
        }
        __syncthreads();
#pragma unroll
        for (int kk = 0; kk < 2; kk++) {
            bfrag af[4], bfr[4];
#pragma unroll
            for (int mt = 0; mt < 4; mt++) {
                int row = wm + mt * 16 + l15;
                af[mt] = *reinterpret_cast<const bfrag*>(
                    &sA[(row * 8 + ((kk * 4 + quad) ^ (row & 7))) * 8]);
            }
#pragma unroll
            for (int nt = 0; nt < 4; nt++) {
                int row = wn + nt * 16 + l15;
                bfr[nt] = *reinterpret_cast<const bfrag*>(
                    &sB[(row * 8 + ((kk * 4 + quad) ^ (row & 7))) * 8]);
            }
#pragma unroll
            for (int mt = 0; mt < 4; mt++)
#pragma unroll
                for (int nt = 0; nt < 4; nt++)
                    acc[mt][nt] = __builtin_amdgcn_mfma_f32_16x16x32_bf16(af[mt], bfr[nt], acc[mt][nt], 0, 0, 0);
        }
        __syncthreads();
    }
    void* Cout = which == 0 ? O0 : (which == 1 ? O1 : O2);
#pragma unroll
    for (int mt = 0; mt < 4; mt++) {
#pragma unroll
        for (int nt = 0; nt < 4; nt++) {
            int cloc = wn + nt * 16 + l15;
            float bb = bias ? bias[w0 + cloc] : 0.f;
            int col = n0 + cloc;
#pragma unroll
            for (int r = 0; r < 4; r++) {
                int row = m0 + wm + mt * 16 + quad * 4 + r;
                float v = acc[mt][nt][r] + bb;
                if (OUTF32) ((float*)Cout)[(size_t)row * Nout + col] = v;
                else        ((bf16*)Cout)[(size_t)row * Nout + col] = f2bf(v);
            }
        }
    }
}

// ---- fused depthwise(KS) + MFMA pointwise, v10 -----------------------------
// v10: sIn channel-padded (+8 elems): channel stride in dwords = 124 (KS5)
// / 84 (KS3) => the 8 lanes' channels hit 8 DISTINCT bank groups (v9's
// NR*20 stride aliased to 2-4 groups = the residual 5.3M conflicts).
// sWm staging vectorized (2x float2 -> uint2).
template <int KS, int MODE>
__device__ __forceinline__ void dwpw_impl(
        char* uMem, float* sWk, __bf16* dwT,
        const bf16* __restrict__ tin, int cOff,
        const float* __restrict__ dw, const float* __restrict__ pw,
        const float* __restrict__ g, const float* __restrict__ b,
        const float* __restrict__ m, const float* __restrict__ v,
        bf16* __restrict__ th, float* __restrict__ rawOut,
        int strip, int bi, int tid) {
    constexpr int WKP = ((KS * KS + 3) / 4) * 4;     // 28 / 12
    constexpr int NR  = KS + 1;                      // staged input rows
    constexpr int CST = NR * 40 + 8;                 // channel stride (elems)
    __bf16* sIn = reinterpret_cast<__bf16*>(uMem);   // [78][CST]
    __bf16* sWm = reinterpret_cast<__bf16*>(uMem);   // [80][104] (after dw)
    const int P = KS / 2;

    // zero pads of sIn rows (uint2 = 4 bf16)
    for (int u = tid; u < SD_ * NR * 2; u += 512) {
        int c = u / (NR * 2);
        int rem = u - c * (NR * 2);
        int di = rem >> 1, side = rem & 1;
        *reinterpret_cast<uint2*>(sIn + c * CST + di * 40 + (side ? 36 : 0)) = make_uint2(0u, 0u);
    }
    // zero the whole dwT (covers K-padding and swizzle spill range)
    for (int u = tid; u < 64 * 128 / 8; u += 512) {
        *reinterpret_cast<uint4*>(dwT + u * 8) = make_uint4(0u, 0u, 0u, 0u);
    }
    // stage NR input rows (zero outside image): uint4 read -> 2x uint2 LDS
    const __bf16* tbase = reinterpret_cast<const __bf16*>(tin) + ((size_t)bi * C_ + cOff) * N_;
    for (int u = tid; u < SD_ * NR * 4; u += 512) {
        int c = u / (NR * 4);
        int rem = u - c * (NR * 4);
        int di = rem >> 2, cb = rem & 3;
        int ii = 2 * strip + di - P;
        uint4 val = make_uint4(0u, 0u, 0u, 0u);
        if (ii >= 0 && ii <= 31)
            val = *reinterpret_cast<const uint4*>(tbase + (size_t)c * N_ + ii * 32 + cb * 8);
        __bf16* dst = sIn + c * CST + di * 40 + 4 + cb * 8;
        *reinterpret_cast<uint2*>(dst)     = make_uint2(val.x, val.y);
        *reinterpret_cast<uint2*>(dst + 4) = make_uint2(val.z, val.w);
    }
    // stage dw weights
    for (int i = tid; i < SD_ * KS * KS; i += 512) {
        int c = i / (KS * KS), q = i - c * (KS * KS);
        sWk[c * WKP + q] = dw[i];
    }
    __syncthreads();

    // dw compute: unit = (c, row 0/1, 8-col group q8) -> dwT swizzled
    for (int u = tid; u < SD_ * 8; u += 512) {
        int c = u >> 3, grp = u & 7;
        int row = grp >> 2, q8 = (grp & 3) << 3;
        const __bf16* rbase = sIn + c * CST + row * 40;
        __bf16 rowv[KS][16];
#pragma unroll
        for (int di = 0; di < KS; di++) {
            *reinterpret_cast<bfrag*>(&rowv[di][0]) = *reinterpret_cast<const bfrag*>(rbase + di * 40 + q8);
            *reinterpret_cast<bfrag*>(&rowv[di][8]) = *reinterpret_cast<const bfrag*>(rbase + di * 40 + q8 + 8);
        }
        float wreg[WKP];
#pragma unroll
        for (int qq = 0; qq < WKP / 4; qq++)
            *reinterpret_cast<float4*>(&wreg[qq * 4]) =
                *reinterpret_cast<const float4*>(&sWk[c * WKP + qq * 4]);
        float acc8[8];
#pragma unroll
        for (int k = 0; k < 8; k++) acc8[k] = 0.f;
#pragma unroll
        for (int di = 0; di < KS; di++) {
#pragma unroll
            for (int dj = 0; dj < KS; dj++) {
                float w = wreg[di * KS + dj];
#pragma unroll
                for (int k = 0; k < 8; k++)
                    acc8[k] += (float)rowv[di][k + dj - P + 4] * w;
            }
        }
#pragma unroll
        for (int k = 0; k < 8; k++)
            dwT[dwt_idx(row * 32 + q8 + k, c)] = (__bf16)acc8[k];
    }
    __syncthreads();

    // stage pw weights bf16 into sWm [80][104]; unit = 4 elems (2x float2)
    for (int u = tid; u < 80 * 26; u += 512) {
        int o = u / 26, c4 = (u - o * 26) * 4;
        __bf16 o4[4];
        if (o < SD_ && c4 + 3 < SD_) {
            float2 w0 = *reinterpret_cast<const float2*>(pw + o * SD_ + c4);
            float2 w1 = *reinterpret_cast<const float2*>(pw + o * SD_ + c4 + 2);
            o4[0] = (__bf16)w0.x; o4[1] = (__bf16)w0.y;
            o4[2] = (__bf16)w1.x; o4[3] = (__bf16)w1.y;
        } else {
#pragma unroll
            for (int j = 0; j < 4; j++) {
                int c = c4 + j;
                o4[j] = (o < SD_ && c < SD_) ? (__bf16)pw[o * SD_ + c] : (__bf16)0.f;
            }
        }
        *reinterpret_cast<uint2*>(sWm + o * 104 + c4) = *reinterpret_cast<const uint2*>(o4);
    }
    __syncthreads();

    // MFMA pw: wave w: n-tile = w&3 (16 pos), m-set = (w>>2)? {3,4} : {0,1,2}
    int lane = tid & 63, wave = tid >> 6;
    int quad = lane >> 4, l15 = lane & 15;
    int wn = wave & 3, mh = wave >> 2;
    int mt0 = mh ? 3 : 0;
    int mcnt = mh ? 2 : 3;
    f32x4 acc[3];
#pragma unroll
    for (int i = 0; i < 3; i++) acc[i] = (f32x4)(0.f);
#pragma unroll
    for (int kk = 0; kk < 3; kk++) {
        int prow = wn * 16 + l15;
        int ch = (kk * 4 + quad) ^ (prow & 7) ^ ((prow >> 3) & 7);
        bfrag bv = *reinterpret_cast<const bfrag*>(dwT + prow * 128 + ch * 8);
#pragma unroll
        for (int mi = 0; mi < 3; mi++) {
            if (mi < mcnt) {
                bfrag av = *reinterpret_cast<const bfrag*>(sWm + ((mt0 + mi) * 16 + l15) * 104 + kk * 32 + quad * 8);
                acc[mi] = __builtin_amdgcn_mfma_f32_16x16x32_bf16(av, bv, acc[mi], 0, 0, 0);
            }
        }
    }
    // epilogue: o = (mt0+mi)*16 + quad*4 + r, pos = wn*16 + l15
    int n = strip * 64 + wn * 16 + l15;
    if (MODE == 0) {
        bf16* base = th + (size_t)bi * H_ * C_ * D_;
#pragma unroll
        for (int mi = 0; mi < 3; mi++) {
            if (mi < mcnt) {
#pragma unroll
                for (int r = 0; r < 4; r++) {
                    int o = (mt0 + mi) * 16 + quad * 4 + r;
                    if (o < SD_) {
                        float inv = g[o] * rsqrtf(v[o] + 1e-5f);
                        float y = hswish((acc[mi][r] - m[o]) * inv + b[o]);
                        base[((n >> 7) * C_ + cOff + o) * D_ + (n & 127)] = f2bf(y);
                    }
                }
            }
        }
    } else {
        float* opr = rawOut + (size_t)bi * SD_ * N_;
#pragma unroll
        for (int mi = 0; mi < 3; mi++) {
            if (mi < mcnt) {
#pragma unroll
                for (int r = 0; r < 4; r++) {
                    int o = (mt0 + mi) * 16 + quad * 4 + r;
                    if (o < SD_) opr[(size_t)o * N_ + n] = acc[mi][r];
                }
            }
        }
    }
}

// ---- all three dw+pw branches + seg0 in ONE launch --------------------------
// grid (B*16, 3 tensors, 4 branches), 512 threads.
// LDS: sIn 38688 (union sWm 16640) + sWk 8736 + dwT 16384 = 63808 B -> 2/CU.
__global__ __launch_bounds__(512) void dwpw_all_kernel(
        const bf16* __restrict__ t0, const bf16* __restrict__ t1,
        const bf16* __restrict__ t2,
        const float* __restrict__ dw1, const float* __restrict__ pw1,
        const float* __restrict__ g1, const float* __restrict__ b1,
        const float* __restrict__ m1, const float* __restrict__ v1,
        const float* __restrict__ dw2, const float* __restrict__ pw2,
        const float* __restrict__ g2, const float* __restrict__ b2,
        const float* __restrict__ m2, const float* __restrict__ v2,
        const float* __restrict__ dw0, const float* __restrict__ pw0,
        const float* __restrict__ g0, const float* __restrict__ b0,
        const float* __restrict__ m0, const float* __restrict__ v0,
        bf16* __restrict__ h0, bf16* __restrict__ h1, bf16* __restrict__ h2,
        float* __restrict__ r0_, float* __restrict__ r1_, float* __restrict__ r2_) {
    __shared__ __align__(16) char uMem[SD_ * (6 * 40 + 8) * sizeof(__bf16)]; // 38688 B
    __shared__ __align__(16) float sWk[SD_ * 28];                            //  8736 B
    __shared__ __align__(16) __bf16 dwT[64 * 128];                           // 16384 B

    int ti = blockIdx.y;
    const bf16* tin = ti == 0 ? t0 : (ti == 1 ? t1 : t2);
    bf16* th = ti == 0 ? h0 : (ti == 1 ? h1 : h2);
    float* rawOut = ti == 0 ? r0_ : (ti == 1 ? r1_ : r2_);
    int strip = blockIdx.x & 15;      // 16 strips of 2 rows (64 positions)
    int bi = blockIdx.x >> 4;         // batch
    int tid = threadIdx.x;
    int branch = blockIdx.z;

    if (branch == 3) {
        // seg0: BN+hswish on raw rows, 64 positions, all 78 channels
        const __bf16* tb = reinterpret_cast<const __bf16*>(tin) + (size_t)bi * C_ * N_;
        __bf16* base = reinterpret_cast<__bf16*>(th) + (size_t)bi * H_ * C_ * D_;
        for (int u = tid; u < SD_ * 16; u += 512) {
            int c = u >> 4, p4 = u & 15;
            int n = strip * 64 + p4 * 4;
            uint2 in2 = *reinterpret_cast<const uint2*>(tb + (size_t)c * N_ + n);
            const __bf16* iv = reinterpret_cast<const __bf16*>(&in2);
            float inv = g0[c] * rsqrtf(v0[c] + 1e-5f);
            float mm = m0[c], bb = b0[c];
            __bf16 o4[4];
#pragma unroll
            for (int j = 0; j < 4; j++)
                o4[j] = (__bf16)hswish(((float)iv[j] - mm) * inv + bb);
            *reinterpret_cast<uint2*>(&base[((n >> 7) * C_ + c) * D_ + (n & 127)]) =
                *reinterpret_cast<const uint2*>(o4);
        }
        return;
    }

    if (branch == 0) {
        dwpw_impl<3, 0>(uMem, sWk, dwT, tin, SD_, dw1, pw1, g1, b1, m1, v1,
                        th, (float*)nullptr, strip, bi, tid);
    } else if (branch == 1) {
        dwpw_impl<5, 0>(uMem, sWk, dwT, tin, 2 * SD_, dw2, pw2, g2, b2, m2, v2,
                        th, (float*)nullptr, strip, bi, tid);
    } else {
        dwpw_impl<3, 1>(uMem, sWk, dwT, tin, 3 * SD_, dw0, pw0,
                        (const float*)nullptr, (const float*)nullptr,
                        (const float*)nullptr, (const float*)nullptr,
                        (bf16*)nullptr, rawOut, strip, bi, tid);
    }
}

// grid (64, 3): stats[ti*128 + bg*2 .. +1]
__global__ void gn_stats_kernel(const float* __restrict__ r0_, const float* __restrict__ r1_,
                                const float* __restrict__ r2_, float* __restrict__ stats) {
    int ti = blockIdx.y;
    const float* tmp2 = ti == 0 ? r0_ : (ti == 1 ? r1_ : r2_);
    int bg = blockIdx.x;
    int bi = bg >> 1, grp = bg & 1;
    const float* p = tmp2 + (size_t)bi * SD_ * N_ + (size_t)grp * 39 * N_;
    float s = 0.f, sq = 0.f;
    const int TOT = 39 * N_;
    for (int i = threadIdx.x * 4; i < TOT; i += 1024) {
        float4 f4 = *reinterpret_cast<const float4*>(p + i);
        s += f4.x + f4.y + f4.z + f4.w;
        sq += f4.x * f4.x + f4.y * f4.y + f4.z * f4.z + f4.w * f4.w;
    }
    __shared__ float rs[256], rq[256];
    rs[threadIdx.x] = s; rq[threadIdx.x] = sq; __syncthreads();
    for (int o = 128; o > 0; o >>= 1) {
        if (threadIdx.x < o) { rs[threadIdx.x] += rs[threadIdx.x + o]; rq[threadIdx.x] += rq[threadIdx.x + o]; }
        __syncthreads();
    }
    if (threadIdx.x == 0) {
        float mu = rs[0] / (float)TOT;
        float var = rq[0] / (float)TOT - mu * mu;
        stats[ti * 128 + bg * 2] = mu;
        stats[ti * 128 + bg * 2 + 1] = rsqrtf(var + 1e-5f);
    }
}

// grid (2496, 3)
__global__ void gn_apply_kernel(const float* __restrict__ r0_, const float* __restrict__ r1_,
                                const float* __restrict__ r2_, const float* __restrict__ stats,
                                const float* __restrict__ gg, const float* __restrict__ gb,
                                bf16* __restrict__ h0, bf16* __restrict__ h1,
                                bf16* __restrict__ h2) {
    int ti = blockIdx.y;
    const float* tmp2 = ti == 0 ? r0_ : (ti == 1 ? r1_ : r2_);
    bf16* th = ti == 0 ? h0 : (ti == 1 ? h1 : h2);
    int bc = blockIdx.x;
    int bi = bc / SD_, c = bc % SD_;
    int grp = c / 39;
    float mu = stats[ti * 128 + (bi * 2 + grp) * 2];
    float rstd = stats[ti * 128 + (bi * 2 + grp) * 2 + 1];
    float sc = gg[c] * rstd;
    float of = gb[c] - mu * sc;
    const float* p = tmp2 + ((size_t)bi * SD_ + c) * N_;
    __bf16* base = reinterpret_cast<__bf16*>(th) + (size_t)bi * H_ * C_ * D_;
    int n = threadIdx.x * 4;
    float4 f4 = *reinterpret_cast<const float4*>(p + n);
    __bf16 o4[4] = { (__bf16)hswish(f4.x * sc + of), (__bf16)hswish(f4.y * sc + of),
                     (__bf16)hswish(f4.z * sc + of), (__bf16)hswish(f4.w * sc + of) };
    *reinterpret_cast<uint2*>(&base[((n >> 7) * C_ + 234 + c) * D_ + (n & 127)]) =
        *reinterpret_cast<const uint2*>(o4);
}

// ---- FUSED attn: scores + GELU + softmax + attn-out + PV -> ctx ------------
#define SLDA 136
#define PLDA 328
__global__ __launch_bounds__(512, 4) void attn_av_kernel(
        const bf16* __restrict__ qh_, const bf16* __restrict__ kh_,
        const bf16* __restrict__ vh_,
        float* __restrict__ attnOut, bf16* __restrict__ ctx) {
    __shared__ __align__(16) char uni[60928];
    __shared__ float smax[64][2];
    __shared__ float ssum[64][2];
    __bf16* sQ = reinterpret_cast<__bf16*>(uni);            // [64][SLDA]
    __bf16* sK = reinterpret_cast<__bf16*>(uni + 17408);    // [160][SLDA]
    __bf16* sP = reinterpret_cast<__bf16*>(uni);            // [64][PLDA]
    __bf16* sV = reinterpret_cast<__bf16*>(uni + 41984);    // [2][8][64][8]
    const __bf16* qh = reinterpret_cast<const __bf16*>(qh_);
    const __bf16* kh = reinterpret_cast<const __bf16*>(kh_);
    const __bf16* vh = reinterpret_cast<const __bf16*>(vh_);

    int strip = blockIdx.x;
    int bh = blockIdx.y;
    int t = threadIdx.x;
    int lane = t & 63, wave = t >> 6;
    int quad = lane >> 4, l15 = lane & 15;
    int wm = wave >> 1;
    int wn = wave & 1;

#pragma unroll
    for (int cc = 0; cc < 2; cc++) {
        int c = t + cc * 512;
        int row = c >> 4, seg = c & 15;
        int src = strip * 64 + row; if (src > 311) src = 311;
        bfrag v = *reinterpret_cast<const bfrag*>(qh + ((size_t)bh * C_ + src) * D_ + seg * 8);
        *reinterpret_cast<bfrag*>(&sQ[row * SLDA + seg * 8]) = v;
    }

    f32x4 acc[10];
#pragma unroll
    for (int i = 0; i < 10; i++) acc[i] = (f32x4)(0.f);

    bfrag af[4];
    bool afLoaded = false;

    for (int half = 0; half < 2; half++) {
        if (half) __syncthreads();
        for (int cc = 0; cc < 5; cc++) {
            int c = t + cc * 512;
            int row = c >> 4, seg = c & 15;
            int src = half * 160 + row;
            bfrag v;
            if (src < C_) {
                v = *reinterpret_cast<const bfrag*>(kh + ((size_t)bh * C_ + src) * D_ + seg * 8);
            } else {
#pragma unroll
                for (int j = 0; j < 8; j++) v[j] = (__bf16)0.f;
            }
            *reinterpret_cast<bfrag*>(&sK[row * SLDA + seg * 8]) = v;
        }
        __syncthreads();
        if (!afLoaded) {
#pragma unroll
            for (int ks = 0; ks < 4; ks++)
                af[ks] = *reinterpret_cast<const bfrag*>(&sQ[(wm * 16 + l15) * SLDA + ks * 32 + quad * 8]);
            afLoaded = true;
        }
#pragma unroll
        for (int ks = 0; ks < 4; ks++) {
#pragma unroll
            for (int jj = 0; jj < 5; jj++) {
                int lr = (wn * 5 + jj) * 16 + l15;
                bfrag bf = *reinterpret_cast<const bfrag*>(&sK[lr * SLDA + ks * 32 + quad * 8]);
                acc[half * 5 + jj] = __builtin_amdgcn_mfma_f32_16x16x32_bf16(af[ks], bf, acc[half * 5 + jj], 0, 0, 0);
            }
        }
    }

    const float scale = 0.08838834764831845f;
    const float inv_sqrt2 = 0.7071067811865475f;
#pragma unroll
    for (int a = 0; a < 10; a++) {
        int gt = (a / 5) * 10 + wn * 5 + (a % 5);
        int col = gt * 16 + l15;
#pragma unroll
        for (int r = 0; r < 4; r++) {
            float v = acc[a][r];
            float ge = 0.5f * v * (1.0f + erff(v * inv_sqrt2));
            float s = ge * scale;
            if (col >= C_) s = -FLT_MAX;
            acc[a][r] = s;
        }
    }
    float mx[4];
#pragma unroll
    for (int r = 0; r < 4; r++) {
        float m = -FLT_MAX;
#pragma unroll
        for (int a = 0; a < 10; a++) m = fmaxf(m, acc[a][r]);
        for (int o = 1; o < 16; o <<= 1) m = fmaxf(m, __shfl_xor(m, o));
        mx[r] = m;
    }
    if (l15 == 0) {
#pragma unroll
        for (int r = 0; r < 4; r++) smax[wm * 16 + quad * 4 + r][wn] = mx[r];
    }
    __syncthreads();
    float sm[4];
#pragma unroll
    for (int r = 0; r < 4; r++) {
        int row = wm * 16 + quad * 4 + r;
        float m = fmaxf(smax[row][0], smax[row][1]);
        float s = 0.f;
#pragma unroll
        for (int a = 0; a < 10; a++) {
            float e = __expf(acc[a][r] - m);
            acc[a][r] = e;
            s += e;
        }
        for (int o = 1; o < 16; o <<= 1) s += __shfl_xor(s, o);
        sm[r] = s;
    }
    if (l15 == 0) {
#pragma unroll
        for (int r = 0; r < 4; r++) ssum[wm * 16 + quad * 4 + r][wn] = sm[r];
    }
    __syncthreads();

#pragma unroll
    for (int r = 0; r < 4; r++) {
        int row = wm * 16 + quad * 4 + r;
        float inv = 1.0f / (ssum[row][0] + ssum[row][1]);
        int grow = strip * 64 + row;
        float* ao = attnOut + ((size_t)bh * C_ + grow) * C_;
#pragma unroll
        for (int a = 0; a < 10; a++) {
            int gt = (a / 5) * 10 + wn * 5 + (a % 5);
            int col = gt * 16 + l15;
            float pv = acc[a][r] * inv;
            if (grow < C_ && col < C_) ao[col] = pv;
            sP[row * PLDA + col] = f2bf(pv);
        }
    }

    // ---- phase 2: PV ----
    f32x4 acc2[4];
#pragma unroll
    for (int i = 0; i < 4; i++) acc2[i] = (f32x4)(0.f);

    auto stageV = [&](int chunk) {
#pragma unroll
        for (int it = 0; it < 2; it++) {
            int g = t + it * 512;
            int d = g & 127;
            int oct = g >> 7;
            int ktl = oct >> 2, quad2 = oct & 3;
            int cb = chunk * 64 + ktl * 32 + quad2 * 8;
            const __bf16* vp = vh + ((size_t)bh * C_ + cb) * D_ + d;
            bfrag v;
            if (cb + 7 < C_) {
#pragma unroll
                for (int j = 0; j < 8; j++) v[j] = vp[(size_t)j * D_];
            } else {
#pragma unroll
                for (int j = 0; j < 8; j++) v[j] = (cb + j < C_) ? vp[(size_t)j * D_] : (__bf16)0.f;
            }
            *reinterpret_cast<bfrag*>(&sV[(((ktl * 8 + (d >> 4)) * 64) + quad2 * 16 + (d & 15)) * 8]) = v;
        }
    };

    stageV(0);
    __syncthreads();

    for (int chunk = 0; chunk < 5; chunk++) {
#pragma unroll
        for (int ktl = 0; ktl < 2; ktl++) {
            bfrag a = *reinterpret_cast<const bfrag*>(
                &sP[(wm * 16 + l15) * PLDA + chunk * 64 + ktl * 32 + quad * 8]);
#pragma unroll
            for (int ntl = 0; ntl < 4; ntl++) {
                int ntg = wn * 4 + ntl;
                bfrag b = *reinterpret_cast<const bfrag*>(&sV[(((ktl * 8 + ntg) * 64) + lane) * 8]);
                acc2[ntl] = __builtin_amdgcn_mfma_f32_16x16x32_bf16(a, b, acc2[ntl], 0, 0, 0);
            }
        }
        if (chunk < 4) {
            __syncthreads();
            stageV(chunk + 1);
            __syncthreads();
        }
    }

    int b = bh >> 3, h = bh & 7;
#pragma unroll
    for (int ntl = 0; ntl < 4; ntl++) {
        int d = wn * 64 + ntl * 16 + l15;
#pragma unroll
        for (int r = 0; r < 4; r++) {
            int c = strip * 64 + wm * 16 + quad * 4 + r;
            if (c < C_) {
                size_t oi = ((size_t)b * C_ + h * 39 + (c >> 3)) * N_ + ((c & 7) << 7) + d;
                ctx[oi] = f2bf(acc2[ntl][r]);
            }
        }
    }
}

// ---------------- L2 row norm (fp32 out), float4 -----------------------------
__global__ void norm_kernel(const float* __restrict__ out3, float* __restrict__ outp) {
    int r = blockIdx.x;
    const float* p = out3 + (size_t)r * N_;
    float4 f4 = *reinterpret_cast<const float4*>(p + threadIdx.x * 4);
    float sq = f4.x * f4.x + f4.y * f4.y + f4.z * f4.z + f4.w * f4.w;
    __shared__ float rq[256];
    rq[threadIdx.x] = sq; __syncthreads();
    for (int o = 128; o > 0; o >>= 1) {
        if (threadIdx.x < o) rq[threadIdx.x] += rq[threadIdx.x + o];
        __syncthreads();
    }
    float inv = 1.0f / fmaxf(sqrtf(rq[0]), 1e-12f);
    float4 o4 = { f4.x * inv, f4.y * inv, f4.z * inv, f4.w * inv };
    *reinterpret_cast<float4*>(outp + (size_t)r * N_ + threadIdx.x * 4) = o4;
}

// ---------------- host orchestration ----------------------------------------
extern "C" void kernel_launch(void* const* d_in, const int* in_sizes, int n_in,
                              void* d_out, int out_size, void* d_ws, size_t ws_size,
                              hipStream_t stream) {
    const float* x      = (const float*)d_in[0];
    const float* ln_q_g = (const float*)d_in[3];
    const float* ln_q_b = (const float*)d_in[4];
    const float* ln_k_g = (const float*)d_in[5];
    const float* ln_k_b = (const float*)d_in[6];
    const float* ln_v_g = (const float*)d_in[7];
    const float* ln_v_b = (const float*)d_in[8];
    const float* w_q    = (const float*)d_in[9];
    const float* w_k    = (const float*)d_in[10];
    const float* w_v    = (const float*)d_in[11];
    const float* w_proj = (const float*)d_in[12];
    const float* b_proj = (const float*)d_in[13];
    const float* dw0    = (const float*)d_in[14];
    const float* pw0    = (const float*)d_in[15];
    const float* gn_g   = (const float*)d_in[16];
    const float* gn_b   = (const float*)d_in[17];
    const float* dw1    = (const float*)d_in[18];
    const float* pw1    = (const float*)d_in[19];
    const float* dw2    = (const float*)d_in[20];
    const float* pw2    = (const float*)d_in[21];
    const float* bn0_g  = (const float*)d_in[22];
    const float* bn0_b  = (const float*)d_in[23];
    const float* bn0_m  = (const float*)d_in[24];
    const float* bn0_v  = (const float*)d_in[25];
    const float* bn1_g  = (const float*)d_in[26];
    const float* bn1_b  = (const float*)d_in[27];
    const float* bn1_m  = (const float*)d_in[28];
    const float* bn1_v  = (const float*)d_in[29];
    const float* bn2_g  = (const float*)d_in[30];
    const float* bn2_b  = (const float*)d_in[31];
    const float* bn2_m  = (const float*)d_in[32];
    const float* bn2_v  = (const float*)d_in[33];

    char* ws = (char*)d_ws;
    size_t off = 0;
    auto alloc = [&](size_t bytes) {
        void* p = ws + off;
        off = (off + bytes + 255) & ~(size_t)255;
        return p;
    };
    const size_t BF_BYTES = (size_t)BC_ * N_ * sizeof(bf16);
    const size_t T2_FLOATS = (size_t)B_ * SD_ * N_;
    bf16*  xn   = (bf16*)alloc(BF_BYTES);
    bf16*  qb   = (bf16*)alloc(BF_BYTES);
    bf16*  kb   = (bf16*)alloc(BF_BYTES);
    bf16*  vb   = (bf16*)alloc(BF_BYTES);
    float* tmp2 = (float*)alloc(3 * T2_FLOATS * sizeof(float));       // 38.3 MB
    float* gnst = (float*)alloc(2048);
    bf16*  wqkv = (bf16*)alloc((size_t)3 * N_ * N_ * sizeof(bf16));   // 6 MB
    float* bias3 = (float*)alloc((size_t)3 * N_ * sizeof(float));
    bf16*  wpb  = (bf16*)alloc((size_t)N_ * N_ * sizeof(bf16));       // 2 MB

    float* out_main = (float*)d_out;
    float* attn_out = out_main + (size_t)BC_ * N_;

    bf16* qh  = xn;
    bf16* kh  = (bf16*)out_main;
    bf16* vh  = kh + (size_t)BC_ * N_;
    bf16* ctx = vb;
    float* out3 = (float*)qb;
    float* r0 = tmp2, *r1 = tmp2 + T2_FLOATS, *r2 = tmp2 + 2 * T2_FLOATS;

    hipLaunchKernelGGL(wcvt_kernel, dim3(4096), dim3(256), 0, stream,
                       w_q, w_k, w_v, w_proj,
                       ln_q_g, ln_q_b, ln_k_g, ln_k_b, ln_v_g, ln_v_b,
                       wqkv, bias3, wpb);
    hipLaunchKernelGGL(ln_kernel, dim3(BC_), dim3(256), 0, stream, x, xn);
    hipLaunchKernelGGL((mfma_gemm_bw<false>), dim3(24 * 78), dim3(256), 0, stream,
                       xn, wqkv, bias3, 24, (void*)qb, (void*)kb, (void*)vb);

    hipLaunchKernelGGL(dwpw_all_kernel, dim3(B_ * 16, 3, 4), dim3(512), 0, stream,
                       qb, kb, vb,
                       dw1, pw1, bn1_g, bn1_b, bn1_m, bn1_v,
                       dw2, pw2, bn2_g, bn2_b, bn2_m, bn2_v,
                       dw0, pw0, bn0_g, bn0_b, bn0_m, bn0_v,
                       qh, kh, vh, r0, r1, r2);
    hipLaunchKernelGGL(gn_stats_kernel, dim3(B_ * 2, 3), dim3(256), 0, stream,
                       r0, r1, r2, gnst);
    hipLaunchKernelGGL(gn_apply_kernel, dim3(B_ * SD_, 3), dim3(256), 0, stream,
                       r0, r1, r2, gnst, gn_g, gn_b, qh, kh, vh);

    hipLaunchKernelGGL(attn_av_kernel, dim3(5, BH_), dim3(512), 0, stream,
                       qh, kh, vh, attn_out, ctx);
    hipLaunchKernelGGL((mfma_gemm_bw<true>), dim3(8 * 78), dim3(256), 0, stream,
                       ctx, wpb, b_proj, 8, (void*)out3, (void*)out3, (void*)out3);
    hipLaunchKernelGGL(norm_kernel, dim3(BC_), dim3(256), 0, stream, out3, out_main);
}